// Round 2
// baseline (1316.403 us; speedup 1.0000x reference)
//
#include <hip/hip_runtime.h>
#include <stdint.h>
#include <stddef.h>

typedef unsigned int u32;
typedef unsigned long long u64;

#define NB 4
#define NLEV 5
#define NCH 72      // A*C = 9*8
#define NREGCH 36   // A*4
#define TOPK 1000
#define NCAND 5000  // NLEV*TOPK
#define NDET 300
#define NSORT 8192
#define SORT_THREADS 512
#define NBINS 4096        // sigmoid in (0,1]: bits>>18 <= 4064
#define SELCAP 8192
#define NMSCHUNK 1000
#define IMGSZ 512.0f
#define SCORE_TH 0.05f
#define NMS_TH 0.5f
#define BBOX_CLIP_F 4.135166556742356f

__constant__ int c_f[NLEV] = {64, 32, 16, 8, 4};

// ---- XLA-CPU-style sigmoid: logistic(x) = 0.5 + 0.5*tanh(0.5*x), fast-tanh poly, no FMA ----
__device__ __forceinline__ float xla_tanh_f32(float x) {
  float ax = fabsf(x);
  float xc = fminf(fmaxf(x, -7.90531110763549805f), 7.90531110763549805f);
  float x2 = __fmul_rn(xc, xc);
  float p = -2.76076847742355e-16f;
  p = __fadd_rn(__fmul_rn(x2, p), 2.00018790482477e-13f);
  p = __fadd_rn(__fmul_rn(x2, p), -8.60467152213735e-11f);
  p = __fadd_rn(__fmul_rn(x2, p), 5.12229709037114e-08f);
  p = __fadd_rn(__fmul_rn(x2, p), 1.48572235717979e-05f);
  p = __fadd_rn(__fmul_rn(x2, p), 6.37261928875436e-04f);
  p = __fadd_rn(__fmul_rn(x2, p), 4.89352455891786e-03f);
  float num = __fmul_rn(xc, p);
  float q = 1.19825839466702e-06f;
  q = __fadd_rn(__fmul_rn(x2, q), 1.18534705686654e-04f);
  q = __fadd_rn(__fmul_rn(x2, q), 2.26843463243900e-03f);
  q = __fadd_rn(__fmul_rn(x2, q), 4.89352518554385e-03f);
  float r = __fdiv_rn(num, q);
  return (ax < 0.0004f) ? x : r;
}
__device__ __forceinline__ float sigmoid_ref(float x) {
  return __fadd_rn(0.5f, __fmul_rn(0.5f, xla_tanh_f32(__fmul_rn(0.5f, x))));
}

// ---- S1: histogram of sigmoid-score bits (bits>>18), per (b,level) ----
__global__ void k_hist(const float* __restrict__ cls, u32* __restrict__ hist,
                       int Nloc, int logNloc2, int level) {
  int b = blockIdx.y;
  int tid = blockIdx.x * blockDim.x + threadIdx.x;
  int Nsc = Nloc * NCH;
  if (tid >= Nsc) return;
  int loc = tid & (Nloc - 1);
  int ch  = tid >> logNloc2;          // logNloc2 = log2(Nloc) = 2*log2(f)
  float logit = cls[((size_t)b * NCH + ch) * Nloc + loc];
  float s = sigmoid_ref(logit);
  u32 bits = __float_as_uint(s);
  int g = b * NLEV + level;
  atomicAdd(&hist[(size_t)g * NBINS + (bits >> 18)], 1u);
}

// ---- S2: cut bin per (b,level): highest-from-top bin where cum >= TOPK ----
__global__ void k_cut(const u32* __restrict__ hist, int* __restrict__ cutbin) {
  int g = blockIdx.x;
  const u32* h = hist + (size_t)g * NBINS;
  __shared__ u32 part[256];
  int t = threadIdx.x;
  u32 s = 0;
  for (int i = 0; i < 16; ++i) s += h[t * 16 + i];
  part[t] = s;
  __syncthreads();
  if (t == 0) {
    u32 c = 0; int T = 0; bool found = false;
    for (int ch = 255; ch >= 0 && !found; --ch) {
      if (c + part[ch] >= TOPK) {
        u32 cc = c;
        for (int bin = ch * 16 + 15; bin >= ch * 16; --bin) {
          cc += h[bin];
          if (cc >= TOPK) { T = bin; found = true; break; }
        }
      } else c += part[ch];
    }
    cutbin[g] = found ? T : 0;
  }
}

// ---- S3: compact elements with bin >= cut ----
__global__ void k_compact(const float* __restrict__ cls, const int* __restrict__ cutbin,
                          u32* __restrict__ selcnt, u64* __restrict__ sel,
                          int Nloc, int logNloc2, int level) {
  int b = blockIdx.y;
  int tid = blockIdx.x * blockDim.x + threadIdx.x;
  int Nsc = Nloc * NCH;
  if (tid >= Nsc) return;
  int loc = tid & (Nloc - 1);
  int ch  = tid >> logNloc2;
  float logit = cls[((size_t)b * NCH + ch) * Nloc + loc];
  float s = sigmoid_ref(logit);
  u32 bits = __float_as_uint(s);
  int g = b * NLEV + level;
  if ((int)(bits >> 18) >= cutbin[g]) {
    u32 pos = atomicAdd(&selcnt[g], 1u);
    if (pos < SELCAP) {
      u32 e = (u32)(loc * NCH + ch);   // flat score index ((y*f+x)*9+a)*8+c
      sel[(size_t)g * SELCAP + pos] = ((u64)bits << 32) | (u32)(~e);
    }
  }
}

// ---- bitonic sort (descending) of NSORT u64 keys in LDS ----
__device__ void bitonic_desc(u64* s) {
  int t = threadIdx.x;
  for (int k = 2; k <= NSORT; k <<= 1) {
    for (int j = k >> 1; j > 0; j >>= 1) {
      __syncthreads();
      for (int i = t; i < NSORT; i += SORT_THREADS) {
        int ixj = i ^ j;
        if (ixj > i) {
          u64 a = s[i], b = s[ixj];
          bool desc = ((i & k) == 0);
          if ((a < b) == desc) { s[i] = b; s[ixj] = a; }
        }
      }
    }
  }
  __syncthreads();
}

// ---- S4: exact per-(b,level) top-1000 by (score desc, idx asc) ----
__global__ __launch_bounds__(SORT_THREADS)
void k_seltop(const u64* __restrict__ sel, const u32* __restrict__ selcnt,
              float* __restrict__ cand_s, u32* __restrict__ cand_t) {
  __shared__ u64 smem[NSORT];
  int g = blockIdx.x;
  int b = g / NLEV, l = g % NLEV;
  u32 m = selcnt[g]; if (m > SELCAP) m = SELCAP;
  for (int i = threadIdx.x; i < NSORT; i += SORT_THREADS)
    smem[i] = (i < (int)m) ? sel[(size_t)g * SELCAP + i] : 0ULL;
  bitonic_desc(smem);
  for (int r = threadIdx.x; r < TOPK; r += SORT_THREADS) {
    u64 key = smem[r];
    u32 bits = (u32)(key >> 32);
    u32 e = ~((u32)key);
    int slot = b * NCAND + l * TOPK + r;
    cand_s[slot] = __uint_as_float(bits);
    cand_t[slot] = ((u32)l << 19) | (e & 0x7FFFFu);
  }
}

// ---- G1: per-image stable sort of 5000 candidates by (score desc, (l,idx) asc) ----
__global__ __launch_bounds__(SORT_THREADS)
void k_gsort(const float* __restrict__ cand_s, const u32* __restrict__ cand_t,
             float* __restrict__ sort_s, u32* __restrict__ sort_t) {
  __shared__ u64 smem[NSORT];
  int b = blockIdx.x;
  for (int i = threadIdx.x; i < NSORT; i += SORT_THREADS) {
    u64 key = 0;
    if (i < NCAND) {
      float s = cand_s[b * NCAND + i];
      if (s > SCORE_TH) {
        u32 t = cand_t[b * NCAND + i];
        key = ((u64)__float_as_uint(s) << 32) | (u32)(~t);
      }
    }
    smem[i] = key;
  }
  bitonic_desc(smem);
  for (int i = threadIdx.x; i < NCAND; i += SORT_THREADS) {
    u64 key = smem[i];
    if (key) {
      sort_s[b * NCAND + i] = __uint_as_float((u32)(key >> 32));
      sort_t[b * NCAND + i] = ~((u32)key);
    } else {
      sort_s[b * NCAND + i] = -1.0f;
      sort_t[b * NCAND + i] = 0xFFFFFFFFu;
    }
  }
}

struct LevelPtrs { const float* reg[NLEV]; const float* anc[NLEV]; };

// ---- G2: decode boxes for sorted candidates (exact _rn arithmetic) ----
__global__ void k_decode(LevelPtrs lp, const float* __restrict__ sort_s,
                         const u32* __restrict__ sort_t,
                         float* __restrict__ sbox, float* __restrict__ slbl) {
  int b = blockIdx.y;
  int i = blockIdx.x * blockDim.x + threadIdx.x;
  if (i >= NCAND) return;
  float s = sort_s[b * NCAND + i];
  float bx0 = 0.f, bx1 = 0.f, bx2 = 0.f, bx3 = 0.f, lbl = 0.f;
  if (s > SCORE_TH) {
    u32 t = sort_t[b * NCAND + i];
    int l = (int)(t >> 19);
    u32 e = t & 0x7FFFFu;
    int c = (int)(e & 7u);
    u32 anc = e >> 3;              // loc*9 + a
    int a = (int)(anc % 9u);
    int loc = (int)(anc / 9u);
    int f = c_f[l];
    int Nloc = f * f;
    const float* rp = lp.reg[l];
    const float* ap = lp.anc[l] + (size_t)anc * 4;
    float r0 = rp[((size_t)b * NREGCH + (a * 4 + 0)) * Nloc + loc];
    float r1 = rp[((size_t)b * NREGCH + (a * 4 + 1)) * Nloc + loc];
    float r2 = rp[((size_t)b * NREGCH + (a * 4 + 2)) * Nloc + loc];
    float r3 = rp[((size_t)b * NREGCH + (a * 4 + 3)) * Nloc + loc];
    float a0 = ap[0], a1 = ap[1], a2 = ap[2], a3 = ap[3];
    float aw = __fsub_rn(a2, a0);
    float ah = __fsub_rn(a3, a1);
    float acx = __fadd_rn(a0, __fmul_rn(0.5f, aw));
    float acy = __fadd_rn(a1, __fmul_rn(0.5f, ah));
    float dw = fminf(r2, BBOX_CLIP_F);
    float dh = fminf(r3, BBOX_CLIP_F);
    float pcx = __fadd_rn(__fmul_rn(r0, aw), acx);
    float pcy = __fadd_rn(__fmul_rn(r1, ah), acy);
    float pw = __fmul_rn(expf(dw), aw);
    float ph = __fmul_rn(expf(dh), ah);
    float hx = __fmul_rn(0.5f, pw);
    float hy = __fmul_rn(0.5f, ph);
    bx0 = fminf(fmaxf(__fsub_rn(pcx, hx), 0.0f), IMGSZ);
    bx1 = fminf(fmaxf(__fsub_rn(pcy, hy), 0.0f), IMGSZ);
    bx2 = fminf(fmaxf(__fadd_rn(pcx, hx), 0.0f), IMGSZ);
    bx3 = fminf(fmaxf(__fadd_rn(pcy, hy), 0.0f), IMGSZ);
    lbl = (float)c;
  }
  float4 v; v.x = bx0; v.y = bx1; v.z = bx2; v.w = bx3;
  ((float4*)sbox)[b * NCAND + i] = v;
  slbl[b * NCAND + i] = lbl;
}

// ---- G3: greedy NMS, one wave per image, kept-list in LDS, early exit at 300 ----
__global__ void k_nms(const float* __restrict__ sort_s, const float* __restrict__ sbox,
                      const float* __restrict__ slbl,
                      int* __restrict__ kept, int* __restrict__ nkept) {
  int b = blockIdx.x;
  int lane = threadIdx.x;           // blockDim = 64 (one wave)
  __shared__ float4 cbox[NMSCHUNK];
  __shared__ float  csc[NMSCHUNK];
  __shared__ float  k0[NDET], k1[NDET], k2[NDET], k3[NDET], ka[NDET];
  int n = 0;
  bool done = false;
  for (int base = 0; base < NCAND && !done; base += NMSCHUNK) {
    __syncthreads();
    for (int i = lane; i < NMSCHUNK; i += 64) {
      int gi = base + i;
      csc[i] = sort_s[b * NCAND + gi];
      float4 v = ((const float4*)sbox)[b * NCAND + gi];
      float off = __fmul_rn(slbl[b * NCAND + gi], IMGSZ + 1.0f);
      v.x = __fadd_rn(v.x, off); v.y = __fadd_rn(v.y, off);
      v.z = __fadd_rn(v.z, off); v.w = __fadd_rn(v.w, off);
      cbox[i] = v;
    }
    __syncthreads();
    for (int i = 0; i < NMSCHUNK; ++i) {
      float s = csc[i];
      if (s <= 0.0f) { done = true; break; }   // sorted: rest invalid too
      float4 q = cbox[i];
      float areaq = __fmul_rn(__fsub_rn(q.z, q.x), __fsub_rn(q.w, q.y));
      bool sup = false;
      for (int k = lane; k < n; k += 64) {
        float p0 = k0[k], p1 = k1[k], p2 = k2[k], p3 = k3[k];
        float ltx = fmaxf(p0, q.x), lty = fmaxf(p1, q.y);
        float rx  = fminf(p2, q.z), ry  = fminf(p3, q.w);
        float ww = fmaxf(__fsub_rn(rx, ltx), 0.0f);
        float hh = fmaxf(__fsub_rn(ry, lty), 0.0f);
        float inter = __fmul_rn(ww, hh);
        float denom = fmaxf(__fsub_rn(__fadd_rn(ka[k], areaq), inter), 1e-7f);
        if (__fdiv_rn(inter, denom) > NMS_TH) sup = true;
      }
      if (__any((int)sup)) continue;
      if (lane == 0) kept[b * NDET + n] = base + i;
      k0[n] = q.x; k1[n] = q.y; k2[n] = q.z; k3[n] = q.w; ka[n] = areaq; // uniform value
      ++n;
      if (n == NDET) { done = true; break; }
    }
  }
  if (lane == 0) nkept[b] = n;
}

// ---- G4: emit outputs: boxes [B,300,4] ++ scores [B,300] ++ labels [B,300] ----
__global__ void k_out(const float* __restrict__ sbox, const float* __restrict__ slbl,
                      const float* __restrict__ sort_s, const int* __restrict__ kept,
                      const int* __restrict__ nkept, float* __restrict__ out) {
  int idx = blockIdx.x * blockDim.x + threadIdx.x;
  if (idx >= NB * NDET) return;
  int b = idx / NDET, k = idx % NDET;
  int n = nkept[b];
  float bx0 = 0.f, bx1 = 0.f, bx2 = 0.f, bx3 = 0.f, sc = 0.f, lb = -1.0f;
  if (k < n) {
    int i = kept[b * NDET + k];
    float4 v = ((const float4*)sbox)[b * NCAND + i];
    bx0 = v.x; bx1 = v.y; bx2 = v.z; bx3 = v.w;
    sc = sort_s[b * NCAND + i];
    lb = slbl[b * NCAND + i];
  }
  out[(size_t)idx * 4 + 0] = bx0;
  out[(size_t)idx * 4 + 1] = bx1;
  out[(size_t)idx * 4 + 2] = bx2;
  out[(size_t)idx * 4 + 3] = bx3;
  out[NB * NDET * 4 + idx] = sc;
  out[NB * NDET * 5 + idx] = lb;
}

extern "C" void kernel_launch(void* const* d_in, const int* in_sizes, int n_in,
                              void* d_out, int out_size, void* d_ws, size_t ws_size,
                              hipStream_t stream) {
  const float* cls[NLEV]; const float* reg[NLEV]; const float* anc[NLEV];
  // dict order (cls,reg,anc per level) vs signature order (all cls, all reg, all anc)
  bool dict_order = (n_in >= 2) && (in_sizes[1] == 4 * NREGCH * 64 * 64);
  for (int l = 0; l < NLEV; ++l) {
    if (dict_order) {
      cls[l] = (const float*)d_in[3 * l + 0];
      reg[l] = (const float*)d_in[3 * l + 1];
      anc[l] = (const float*)d_in[3 * l + 2];
    } else {
      cls[l] = (const float*)d_in[l];
      reg[l] = (const float*)d_in[NLEV + l];
      anc[l] = (const float*)d_in[2 * NLEV + l];
    }
  }

  char* ws = (char*)d_ws;
  size_t off = 0;
  auto alloc = [&](size_t bytes) -> void* {
    void* p = ws + off;
    off = (off + bytes + 255) & ~(size_t)255;
    return p;
  };
  u32*   selcnt = (u32*)  alloc(20 * 4);
  u32*   hist   = (u32*)  alloc(20ULL * NBINS * 4);
  int*   cutbin = (int*)  alloc(20 * 4);
  u64*   sel    = (u64*)  alloc(20ULL * SELCAP * 8);
  float* cand_s = (float*)alloc((size_t)NB * NCAND * 4);
  u32*   cand_t = (u32*)  alloc((size_t)NB * NCAND * 4);
  float* sort_s = (float*)alloc((size_t)NB * NCAND * 4);
  u32*   sort_t = (u32*)  alloc((size_t)NB * NCAND * 4);
  float* sbox   = (float*)alloc((size_t)NB * NCAND * 16);
  float* slbl   = (float*)alloc((size_t)NB * NCAND * 4);
  int*   kept   = (int*)  alloc((size_t)NB * NDET * 4);
  int*   nkept  = (int*)  alloc(NB * 4);
  (void)ws_size; (void)out_size;

  // zero selcnt + hist (contiguous from ws base through end of hist)
  size_t zero_bytes = (size_t)((char*)cutbin - (char*)selcnt);
  hipMemsetAsync(selcnt, 0, zero_bytes, stream);

  int fs[NLEV]  = {64, 32, 16, 8, 4};
  int lg2[NLEV] = {12, 10, 8, 6, 4};   // log2(f*f)  (round-1 bugfix: was log2(f))
  for (int l = 0; l < NLEV; ++l) {
    int Nloc = fs[l] * fs[l];
    int Nsc = Nloc * NCH;
    dim3 g((Nsc + 255) / 256, NB);
    k_hist<<<g, 256, 0, stream>>>(cls[l], hist, Nloc, lg2[l], l);
  }
  k_cut<<<20, 256, 0, stream>>>(hist, cutbin);
  for (int l = 0; l < NLEV; ++l) {
    int Nloc = fs[l] * fs[l];
    int Nsc = Nloc * NCH;
    dim3 g((Nsc + 255) / 256, NB);
    k_compact<<<g, 256, 0, stream>>>(cls[l], cutbin, selcnt, sel, Nloc, lg2[l], l);
  }
  k_seltop<<<20, SORT_THREADS, 0, stream>>>(sel, selcnt, cand_s, cand_t);
  k_gsort<<<NB, SORT_THREADS, 0, stream>>>(cand_s, cand_t, sort_s, sort_t);

  LevelPtrs lp;
  for (int l = 0; l < NLEV; ++l) { lp.reg[l] = reg[l]; lp.anc[l] = anc[l]; }
  k_decode<<<dim3((NCAND + 127) / 128, NB), 128, 0, stream>>>(lp, sort_s, sort_t, sbox, slbl);
  k_nms<<<NB, 64, 0, stream>>>(sort_s, sbox, slbl, kept, nkept);
  k_out<<<(NB * NDET + 255) / 256, 256, 0, stream>>>(sbox, slbl, sort_s, kept, nkept, (float*)d_out);
}

// Round 3
// 646.282 us; speedup vs baseline: 2.0369x; 2.0369x over previous
//
#include <hip/hip_runtime.h>
#include <stdint.h>
#include <stddef.h>

typedef unsigned int u32;
typedef unsigned long long u64;

#define NB 4
#define NLEV 5
#define NCH 72      // A*C = 9*8
#define NREGCH 36   // A*4
#define TOPK 1000
#define NCAND 5000  // NLEV*TOPK
#define NDET 300
#define NSORT 8192
#define SORT_THREADS 512
#define NBINS 4096        // sigmoid in (0,1]: bits>>18 <= 4064
#define SELCAP 8192
#define NMSCHUNK 1000
#define CHUNK 8192        // elements per histogram/compact block
#define NCHUNK_IMG 50     // 36+9+3+1+1 chunks per image across levels
#define IMGSZ 512.0f
#define SCORE_TH 0.05f
#define NMS_TH 0.5f
#define BBOX_CLIP_F 4.135166556742356f

__constant__ int c_f[NLEV] = {64, 32, 16, 8, 4};

// ---- XLA-CPU-style sigmoid: logistic(x) = 0.5 + 0.5*tanh(0.5*x), fast-tanh poly, no FMA ----
__device__ __forceinline__ float xla_tanh_f32(float x) {
  float ax = fabsf(x);
  float xc = fminf(fmaxf(x, -7.90531110763549805f), 7.90531110763549805f);
  float x2 = __fmul_rn(xc, xc);
  float p = -2.76076847742355e-16f;
  p = __fadd_rn(__fmul_rn(x2, p), 2.00018790482477e-13f);
  p = __fadd_rn(__fmul_rn(x2, p), -8.60467152213735e-11f);
  p = __fadd_rn(__fmul_rn(x2, p), 5.12229709037114e-08f);
  p = __fadd_rn(__fmul_rn(x2, p), 1.48572235717979e-05f);
  p = __fadd_rn(__fmul_rn(x2, p), 6.37261928875436e-04f);
  p = __fadd_rn(__fmul_rn(x2, p), 4.89352455891786e-03f);
  float num = __fmul_rn(xc, p);
  float q = 1.19825839466702e-06f;
  q = __fadd_rn(__fmul_rn(x2, q), 1.18534705686654e-04f);
  q = __fadd_rn(__fmul_rn(x2, q), 2.26843463243900e-03f);
  q = __fadd_rn(__fmul_rn(x2, q), 4.89352518554385e-03f);
  float r = __fdiv_rn(num, q);
  return (ax < 0.0004f) ? x : r;
}
__device__ __forceinline__ float sigmoid_ref(float x) {
  return __fadd_rn(0.5f, __fmul_rn(0.5f, xla_tanh_f32(__fmul_rn(0.5f, x))));
}

struct ClsPtrs { const float* p[NLEV]; };
struct LevelPtrs { const float* reg[NLEV]; const float* anc[NLEV]; };

// block → (b, level, chunk) mapping for the fused hist/compact grids
__device__ __forceinline__ void chunk_map(int bid, int& b, int& level, int& chunk) {
  b = bid / NCHUNK_IMG;
  int cid = bid % NCHUNK_IMG;
  if      (cid < 36) { level = 0; chunk = cid; }
  else if (cid < 45) { level = 1; chunk = cid - 36; }
  else if (cid < 48) { level = 2; chunk = cid - 45; }
  else if (cid < 49) { level = 3; chunk = cid - 48; }
  else               { level = 4; chunk = cid - 49; }
}
__constant__ int c_Nloc[NLEV] = {4096, 1024, 256, 64, 16};
__constant__ int c_lg2[NLEV]  = {12, 10, 8, 6, 4};

// ---- S1: fused LDS-privatized histogram of sigmoid bits (bits>>18), per (b,level) ----
__global__ __launch_bounds__(256)
void k_hist(ClsPtrs cp, u32* __restrict__ hist) {
  int b, level, chunk;
  chunk_map(blockIdx.x, b, level, chunk);
  int Nloc = c_Nloc[level];
  int Nsc = Nloc * NCH;
  __shared__ u32 lh[NBINS];
  for (int i = threadIdx.x; i < NBINS; i += 256) lh[i] = 0;
  __syncthreads();
  const float* cls = cp.p[level] + (size_t)b * Nsc;   // [72][Nloc] flat
  int base = chunk * CHUNK;
  int end = base + CHUNK; if (end > Nsc) end = Nsc;
  for (int i = base + threadIdx.x; i < end; i += 256) {
    float s = sigmoid_ref(cls[i]);
    atomicAdd(&lh[__float_as_uint(s) >> 18], 1u);
  }
  __syncthreads();
  u32* gh = hist + (size_t)(b * NLEV + level) * NBINS;
  for (int i = threadIdx.x; i < NBINS; i += 256) {
    u32 v = lh[i];
    if (v) atomicAdd(&gh[i], v);
  }
}

// ---- S2: cut bin per (b,level): highest-from-top bin where cum >= TOPK ----
__global__ void k_cut(const u32* __restrict__ hist, int* __restrict__ cutbin) {
  int g = blockIdx.x;
  const u32* h = hist + (size_t)g * NBINS;
  __shared__ u32 part[256];
  int t = threadIdx.x;
  u32 s = 0;
  for (int i = 0; i < 16; ++i) s += h[t * 16 + i];
  part[t] = s;
  __syncthreads();
  if (t == 0) {
    u32 c = 0; int T = 0; bool found = false;
    for (int ch = 255; ch >= 0 && !found; --ch) {
      if (c + part[ch] >= TOPK) {
        u32 cc = c;
        for (int bin = ch * 16 + 15; bin >= ch * 16; --bin) {
          cc += h[bin];
          if (cc >= TOPK) { T = bin; found = true; break; }
        }
      } else c += part[ch];
    }
    cutbin[g] = found ? T : 0;
  }
}

// ---- S3: fused compact of elements with bin >= cut ----
__global__ __launch_bounds__(256)
void k_compact(ClsPtrs cp, const int* __restrict__ cutbin,
               u32* __restrict__ selcnt, u64* __restrict__ sel) {
  int b, level, chunk;
  chunk_map(blockIdx.x, b, level, chunk);
  int Nloc = c_Nloc[level];
  int lg2 = c_lg2[level];
  int Nsc = Nloc * NCH;
  int g = b * NLEV + level;
  int cut = cutbin[g];
  const float* cls = cp.p[level] + (size_t)b * Nsc;
  int base = chunk * CHUNK;
  int end = base + CHUNK; if (end > Nsc) end = Nsc;
  for (int i = base + threadIdx.x; i < end; i += 256) {
    float s = sigmoid_ref(cls[i]);
    u32 bits = __float_as_uint(s);
    if ((int)(bits >> 18) >= cut) {
      u32 pos = atomicAdd(&selcnt[g], 1u);
      if (pos < SELCAP) {
        int ch = i >> lg2;
        int loc = i & (Nloc - 1);
        u32 e = (u32)(loc * NCH + ch);   // flat score index ((y*f+x)*9+a)*8+c
        sel[(size_t)g * SELCAP + pos] = ((u64)bits << 32) | (u32)(~e);
      }
    }
  }
}

// ---- bitonic sort (descending) of NSORT u64 keys in LDS ----
__device__ void bitonic_desc(u64* s) {
  int t = threadIdx.x;
  for (int k = 2; k <= NSORT; k <<= 1) {
    for (int j = k >> 1; j > 0; j >>= 1) {
      __syncthreads();
      for (int i = t; i < NSORT; i += SORT_THREADS) {
        int ixj = i ^ j;
        if (ixj > i) {
          u64 a = s[i], b = s[ixj];
          bool desc = ((i & k) == 0);
          if ((a < b) == desc) { s[i] = b; s[ixj] = a; }
        }
      }
    }
  }
  __syncthreads();
}

// ---- S4: exact per-(b,level) top-1000 by (score desc, idx asc) ----
__global__ __launch_bounds__(SORT_THREADS)
void k_seltop(const u64* __restrict__ sel, const u32* __restrict__ selcnt,
              float* __restrict__ cand_s, u32* __restrict__ cand_t) {
  __shared__ u64 smem[NSORT];
  int g = blockIdx.x;
  int b = g / NLEV, l = g % NLEV;
  u32 m = selcnt[g]; if (m > SELCAP) m = SELCAP;
  for (int i = threadIdx.x; i < NSORT; i += SORT_THREADS)
    smem[i] = (i < (int)m) ? sel[(size_t)g * SELCAP + i] : 0ULL;
  bitonic_desc(smem);
  for (int r = threadIdx.x; r < TOPK; r += SORT_THREADS) {
    u64 key = smem[r];
    u32 bits = (u32)(key >> 32);
    u32 e = ~((u32)key);
    int slot = b * NCAND + l * TOPK + r;
    cand_s[slot] = __uint_as_float(bits);
    cand_t[slot] = ((u32)l << 19) | (e & 0x7FFFFu);
  }
}

// ---- G1: per-image stable sort of 5000 candidates by (score desc, (l,idx) asc) ----
__global__ __launch_bounds__(SORT_THREADS)
void k_gsort(const float* __restrict__ cand_s, const u32* __restrict__ cand_t,
             float* __restrict__ sort_s, u32* __restrict__ sort_t) {
  __shared__ u64 smem[NSORT];
  int b = blockIdx.x;
  for (int i = threadIdx.x; i < NSORT; i += SORT_THREADS) {
    u64 key = 0;
    if (i < NCAND) {
      float s = cand_s[b * NCAND + i];
      if (s > SCORE_TH) {
        u32 t = cand_t[b * NCAND + i];
        key = ((u64)__float_as_uint(s) << 32) | (u32)(~t);
      }
    }
    smem[i] = key;
  }
  bitonic_desc(smem);
  for (int i = threadIdx.x; i < NCAND; i += SORT_THREADS) {
    u64 key = smem[i];
    if (key) {
      sort_s[b * NCAND + i] = __uint_as_float((u32)(key >> 32));
      sort_t[b * NCAND + i] = ~((u32)key);
    } else {
      sort_s[b * NCAND + i] = -1.0f;
      sort_t[b * NCAND + i] = 0xFFFFFFFFu;
    }
  }
}

// ---- G2: decode boxes for sorted candidates (exact _rn arithmetic) ----
__global__ void k_decode(LevelPtrs lp, const float* __restrict__ sort_s,
                         const u32* __restrict__ sort_t,
                         float* __restrict__ sbox, float* __restrict__ slbl) {
  int b = blockIdx.y;
  int i = blockIdx.x * blockDim.x + threadIdx.x;
  if (i >= NCAND) return;
  float s = sort_s[b * NCAND + i];
  float bx0 = 0.f, bx1 = 0.f, bx2 = 0.f, bx3 = 0.f, lbl = 0.f;
  if (s > SCORE_TH) {
    u32 t = sort_t[b * NCAND + i];
    int l = (int)(t >> 19);
    u32 e = t & 0x7FFFFu;
    int c = (int)(e & 7u);
    u32 anc = e >> 3;              // loc*9 + a
    int a = (int)(anc % 9u);
    int loc = (int)(anc / 9u);
    int f = c_f[l];
    int Nloc = f * f;
    const float* rp = lp.reg[l];
    const float* ap = lp.anc[l] + (size_t)anc * 4;
    float r0 = rp[((size_t)b * NREGCH + (a * 4 + 0)) * Nloc + loc];
    float r1 = rp[((size_t)b * NREGCH + (a * 4 + 1)) * Nloc + loc];
    float r2 = rp[((size_t)b * NREGCH + (a * 4 + 2)) * Nloc + loc];
    float r3 = rp[((size_t)b * NREGCH + (a * 4 + 3)) * Nloc + loc];
    float a0 = ap[0], a1 = ap[1], a2 = ap[2], a3 = ap[3];
    float aw = __fsub_rn(a2, a0);
    float ah = __fsub_rn(a3, a1);
    float acx = __fadd_rn(a0, __fmul_rn(0.5f, aw));
    float acy = __fadd_rn(a1, __fmul_rn(0.5f, ah));
    float dw = fminf(r2, BBOX_CLIP_F);
    float dh = fminf(r3, BBOX_CLIP_F);
    float pcx = __fadd_rn(__fmul_rn(r0, aw), acx);
    float pcy = __fadd_rn(__fmul_rn(r1, ah), acy);
    float pw = __fmul_rn(expf(dw), aw);
    float ph = __fmul_rn(expf(dh), ah);
    float hx = __fmul_rn(0.5f, pw);
    float hy = __fmul_rn(0.5f, ph);
    bx0 = fminf(fmaxf(__fsub_rn(pcx, hx), 0.0f), IMGSZ);
    bx1 = fminf(fmaxf(__fsub_rn(pcy, hy), 0.0f), IMGSZ);
    bx2 = fminf(fmaxf(__fadd_rn(pcx, hx), 0.0f), IMGSZ);
    bx3 = fminf(fmaxf(__fadd_rn(pcy, hy), 0.0f), IMGSZ);
    lbl = (float)c;
  }
  float4 v; v.x = bx0; v.y = bx1; v.z = bx2; v.w = bx3;
  ((float4*)sbox)[b * NCAND + i] = v;
  slbl[b * NCAND + i] = lbl;
}

// ---- G3: greedy NMS, one wave per image, kept-list in LDS, early exit at 300 ----
__global__ void k_nms(const float* __restrict__ sort_s, const float* __restrict__ sbox,
                      const float* __restrict__ slbl,
                      int* __restrict__ kept, int* __restrict__ nkept) {
  int b = blockIdx.x;
  int lane = threadIdx.x;           // blockDim = 64 (one wave)
  __shared__ float4 cbox[NMSCHUNK];
  __shared__ float  csc[NMSCHUNK];
  __shared__ float  k0[NDET], k1[NDET], k2[NDET], k3[NDET], ka[NDET];
  int n = 0;
  bool done = false;
  for (int base = 0; base < NCAND && !done; base += NMSCHUNK) {
    __syncthreads();
    for (int i = lane; i < NMSCHUNK; i += 64) {
      int gi = base + i;
      csc[i] = sort_s[b * NCAND + gi];
      float4 v = ((const float4*)sbox)[b * NCAND + gi];
      float off = __fmul_rn(slbl[b * NCAND + gi], IMGSZ + 1.0f);
      v.x = __fadd_rn(v.x, off); v.y = __fadd_rn(v.y, off);
      v.z = __fadd_rn(v.z, off); v.w = __fadd_rn(v.w, off);
      cbox[i] = v;
    }
    __syncthreads();
    for (int i = 0; i < NMSCHUNK; ++i) {
      float s = csc[i];
      if (s <= 0.0f) { done = true; break; }   // sorted: rest invalid too
      float4 q = cbox[i];
      float areaq = __fmul_rn(__fsub_rn(q.z, q.x), __fsub_rn(q.w, q.y));
      bool sup = false;
      for (int k = lane; k < n; k += 64) {
        float p0 = k0[k], p1 = k1[k], p2 = k2[k], p3 = k3[k];
        float ltx = fmaxf(p0, q.x), lty = fmaxf(p1, q.y);
        float rx  = fminf(p2, q.z), ry  = fminf(p3, q.w);
        float ww = fmaxf(__fsub_rn(rx, ltx), 0.0f);
        float hh = fmaxf(__fsub_rn(ry, lty), 0.0f);
        float inter = __fmul_rn(ww, hh);
        float denom = fmaxf(__fsub_rn(__fadd_rn(ka[k], areaq), inter), 1e-7f);
        if (__fdiv_rn(inter, denom) > NMS_TH) sup = true;
      }
      if (__any((int)sup)) continue;
      if (lane == 0) kept[b * NDET + n] = base + i;
      k0[n] = q.x; k1[n] = q.y; k2[n] = q.z; k3[n] = q.w; ka[n] = areaq; // uniform value
      ++n;
      if (n == NDET) { done = true; break; }
    }
  }
  if (lane == 0) nkept[b] = n;
}

// ---- G4: emit outputs: boxes [B,300,4] ++ scores [B,300] ++ labels [B,300] ----
__global__ void k_out(const float* __restrict__ sbox, const float* __restrict__ slbl,
                      const float* __restrict__ sort_s, const int* __restrict__ kept,
                      const int* __restrict__ nkept, float* __restrict__ out) {
  int idx = blockIdx.x * blockDim.x + threadIdx.x;
  if (idx >= NB * NDET) return;
  int b = idx / NDET, k = idx % NDET;
  int n = nkept[b];
  float bx0 = 0.f, bx1 = 0.f, bx2 = 0.f, bx3 = 0.f, sc = 0.f, lb = -1.0f;
  if (k < n) {
    int i = kept[b * NDET + k];
    float4 v = ((const float4*)sbox)[b * NCAND + i];
    bx0 = v.x; bx1 = v.y; bx2 = v.z; bx3 = v.w;
    sc = sort_s[b * NCAND + i];
    lb = slbl[b * NCAND + i];
  }
  out[(size_t)idx * 4 + 0] = bx0;
  out[(size_t)idx * 4 + 1] = bx1;
  out[(size_t)idx * 4 + 2] = bx2;
  out[(size_t)idx * 4 + 3] = bx3;
  out[NB * NDET * 4 + idx] = sc;
  out[NB * NDET * 5 + idx] = lb;
}

extern "C" void kernel_launch(void* const* d_in, const int* in_sizes, int n_in,
                              void* d_out, int out_size, void* d_ws, size_t ws_size,
                              hipStream_t stream) {
  const float* cls[NLEV]; const float* reg[NLEV]; const float* anc[NLEV];
  // dict order (cls,reg,anc per level) vs signature order (all cls, all reg, all anc)
  bool dict_order = (n_in >= 2) && (in_sizes[1] == 4 * NREGCH * 64 * 64);
  for (int l = 0; l < NLEV; ++l) {
    if (dict_order) {
      cls[l] = (const float*)d_in[3 * l + 0];
      reg[l] = (const float*)d_in[3 * l + 1];
      anc[l] = (const float*)d_in[3 * l + 2];
    } else {
      cls[l] = (const float*)d_in[l];
      reg[l] = (const float*)d_in[NLEV + l];
      anc[l] = (const float*)d_in[2 * NLEV + l];
    }
  }

  char* ws = (char*)d_ws;
  size_t off = 0;
  auto alloc = [&](size_t bytes) -> void* {
    void* p = ws + off;
    off = (off + bytes + 255) & ~(size_t)255;
    return p;
  };
  u32*   selcnt = (u32*)  alloc(20 * 4);
  u32*   hist   = (u32*)  alloc(20ULL * NBINS * 4);
  int*   cutbin = (int*)  alloc(20 * 4);
  u64*   sel    = (u64*)  alloc(20ULL * SELCAP * 8);
  float* cand_s = (float*)alloc((size_t)NB * NCAND * 4);
  u32*   cand_t = (u32*)  alloc((size_t)NB * NCAND * 4);
  float* sort_s = (float*)alloc((size_t)NB * NCAND * 4);
  u32*   sort_t = (u32*)  alloc((size_t)NB * NCAND * 4);
  float* sbox   = (float*)alloc((size_t)NB * NCAND * 16);
  float* slbl   = (float*)alloc((size_t)NB * NCAND * 4);
  int*   kept   = (int*)  alloc((size_t)NB * NDET * 4);
  int*   nkept  = (int*)  alloc(NB * 4);
  (void)ws_size; (void)out_size;

  // zero selcnt + hist (contiguous from ws base through end of hist)
  size_t zero_bytes = (size_t)((char*)cutbin - (char*)selcnt);
  hipMemsetAsync(selcnt, 0, zero_bytes, stream);

  ClsPtrs cp;
  for (int l = 0; l < NLEV; ++l) cp.p[l] = cls[l];

  k_hist<<<NB * NCHUNK_IMG, 256, 0, stream>>>(cp, hist);
  k_cut<<<20, 256, 0, stream>>>(hist, cutbin);
  k_compact<<<NB * NCHUNK_IMG, 256, 0, stream>>>(cp, cutbin, selcnt, sel);
  k_seltop<<<20, SORT_THREADS, 0, stream>>>(sel, selcnt, cand_s, cand_t);
  k_gsort<<<NB, SORT_THREADS, 0, stream>>>(cand_s, cand_t, sort_s, sort_t);

  LevelPtrs lp;
  for (int l = 0; l < NLEV; ++l) { lp.reg[l] = reg[l]; lp.anc[l] = anc[l]; }
  k_decode<<<dim3((NCAND + 127) / 128, NB), 128, 0, stream>>>(lp, sort_s, sort_t, sbox, slbl);
  k_nms<<<NB, 64, 0, stream>>>(sort_s, sbox, slbl, kept, nkept);
  k_out<<<(NB * NDET + 255) / 256, 256, 0, stream>>>(sbox, slbl, sort_s, kept, nkept, (float*)d_out);
}

// Round 4
// 635.625 us; speedup vs baseline: 2.0710x; 1.0168x over previous
//
#include <hip/hip_runtime.h>
#include <stdint.h>
#include <stddef.h>

typedef unsigned int u32;
typedef unsigned long long u64;

#define NB 4
#define NLEV 5
#define NCH 72      // A*C = 9*8
#define NREGCH 36   // A*4
#define TOPK 1000
#define NCAND 5000  // NLEV*TOPK
#define NDET 300
#define NSORT 8192
#define SORT_THREADS 512
#define NBINS 4096        // sigmoid in (0,1]: bits>>18 <= 4064
#define SELCAP 8192
#define CHUNK 8192        // elements per histogram/compact block
#define NCHUNK_IMG 50     // 36+9+3+1+1 chunks per image across levels
#define IMGSZ 512.0f
#define SCORE_TH 0.05f
#define NMS_TH 0.5f
#define BBOX_CLIP_F 4.135166556742356f

__constant__ int c_f[NLEV] = {64, 32, 16, 8, 4};

// ---- XLA-CPU-style sigmoid: logistic(x) = 0.5 + 0.5*tanh(0.5*x), fast-tanh poly, no FMA ----
__device__ __forceinline__ float xla_tanh_f32(float x) {
  float ax = fabsf(x);
  float xc = fminf(fmaxf(x, -7.90531110763549805f), 7.90531110763549805f);
  float x2 = __fmul_rn(xc, xc);
  float p = -2.76076847742355e-16f;
  p = __fadd_rn(__fmul_rn(x2, p), 2.00018790482477e-13f);
  p = __fadd_rn(__fmul_rn(x2, p), -8.60467152213735e-11f);
  p = __fadd_rn(__fmul_rn(x2, p), 5.12229709037114e-08f);
  p = __fadd_rn(__fmul_rn(x2, p), 1.48572235717979e-05f);
  p = __fadd_rn(__fmul_rn(x2, p), 6.37261928875436e-04f);
  p = __fadd_rn(__fmul_rn(x2, p), 4.89352455891786e-03f);
  float num = __fmul_rn(xc, p);
  float q = 1.19825839466702e-06f;
  q = __fadd_rn(__fmul_rn(x2, q), 1.18534705686654e-04f);
  q = __fadd_rn(__fmul_rn(x2, q), 2.26843463243900e-03f);
  q = __fadd_rn(__fmul_rn(x2, q), 4.89352518554385e-03f);
  float r = __fdiv_rn(num, q);
  return (ax < 0.0004f) ? x : r;
}
__device__ __forceinline__ float sigmoid_ref(float x) {
  return __fadd_rn(0.5f, __fmul_rn(0.5f, xla_tanh_f32(__fmul_rn(0.5f, x))));
}

struct ClsPtrs { const float* p[NLEV]; };
struct LevelPtrs { const float* reg[NLEV]; const float* anc[NLEV]; };

// block → (b, level, chunk) mapping for the fused hist/compact grids
__device__ __forceinline__ void chunk_map(int bid, int& b, int& level, int& chunk) {
  b = bid / NCHUNK_IMG;
  int cid = bid % NCHUNK_IMG;
  if      (cid < 36) { level = 0; chunk = cid; }
  else if (cid < 45) { level = 1; chunk = cid - 36; }
  else if (cid < 48) { level = 2; chunk = cid - 45; }
  else if (cid < 49) { level = 3; chunk = cid - 48; }
  else               { level = 4; chunk = cid - 49; }
}
__constant__ int c_Nloc[NLEV] = {4096, 1024, 256, 64, 16};
__constant__ int c_lg2[NLEV]  = {12, 10, 8, 6, 4};

// ---- S1: fused LDS-privatized histogram of sigmoid bits (bits>>18), per (b,level) ----
__global__ __launch_bounds__(256)
void k_hist(ClsPtrs cp, u32* __restrict__ hist) {
  int b, level, chunk;
  chunk_map(blockIdx.x, b, level, chunk);
  int Nloc = c_Nloc[level];
  int Nsc = Nloc * NCH;
  __shared__ u32 lh[NBINS];
  for (int i = threadIdx.x; i < NBINS; i += 256) lh[i] = 0;
  __syncthreads();
  const float* cls = cp.p[level] + (size_t)b * Nsc;   // [72][Nloc] flat
  int base = chunk * CHUNK;
  int end = base + CHUNK; if (end > Nsc) end = Nsc;
  for (int i = base + threadIdx.x; i < end; i += 256) {
    float s = sigmoid_ref(cls[i]);
    atomicAdd(&lh[__float_as_uint(s) >> 18], 1u);
  }
  __syncthreads();
  u32* gh = hist + (size_t)(b * NLEV + level) * NBINS;
  for (int i = threadIdx.x; i < NBINS; i += 256) {
    u32 v = lh[i];
    if (v) atomicAdd(&gh[i], v);
  }
}

// ---- S2: cut bin per (b,level): highest-from-top bin where cum >= TOPK ----
__global__ void k_cut(const u32* __restrict__ hist, int* __restrict__ cutbin) {
  int g = blockIdx.x;
  const u32* h = hist + (size_t)g * NBINS;
  __shared__ u32 part[256];
  int t = threadIdx.x;
  u32 s = 0;
  for (int i = 0; i < 16; ++i) s += h[t * 16 + i];
  part[t] = s;
  __syncthreads();
  if (t == 0) {
    u32 c = 0; int T = 0; bool found = false;
    for (int ch = 255; ch >= 0 && !found; --ch) {
      if (c + part[ch] >= TOPK) {
        u32 cc = c;
        for (int bin = ch * 16 + 15; bin >= ch * 16; --bin) {
          cc += h[bin];
          if (cc >= TOPK) { T = bin; found = true; break; }
        }
      } else c += part[ch];
    }
    cutbin[g] = found ? T : 0;
  }
}

// ---- S3: fused compact of elements with bin >= cut ----
__global__ __launch_bounds__(256)
void k_compact(ClsPtrs cp, const int* __restrict__ cutbin,
               u32* __restrict__ selcnt, u64* __restrict__ sel) {
  int b, level, chunk;
  chunk_map(blockIdx.x, b, level, chunk);
  int Nloc = c_Nloc[level];
  int lg2 = c_lg2[level];
  int Nsc = Nloc * NCH;
  int g = b * NLEV + level;
  int cut = cutbin[g];
  const float* cls = cp.p[level] + (size_t)b * Nsc;
  int base = chunk * CHUNK;
  int end = base + CHUNK; if (end > Nsc) end = Nsc;
  for (int i = base + threadIdx.x; i < end; i += 256) {
    float s = sigmoid_ref(cls[i]);
    u32 bits = __float_as_uint(s);
    if ((int)(bits >> 18) >= cut) {
      u32 pos = atomicAdd(&selcnt[g], 1u);
      if (pos < SELCAP) {
        int ch = i >> lg2;
        int loc = i & (Nloc - 1);
        u32 e = (u32)(loc * NCH + ch);   // flat score index ((y*f+x)*9+a)*8+c
        sel[(size_t)g * SELCAP + pos] = ((u64)bits << 32) | (u32)(~e);
      }
    }
  }
}

// ---- bitonic sort (descending) of NSORT u64 keys in LDS ----
__device__ void bitonic_desc(u64* s) {
  int t = threadIdx.x;
  for (int k = 2; k <= NSORT; k <<= 1) {
    for (int j = k >> 1; j > 0; j >>= 1) {
      __syncthreads();
      for (int i = t; i < NSORT; i += SORT_THREADS) {
        int ixj = i ^ j;
        if (ixj > i) {
          u64 a = s[i], b = s[ixj];
          bool desc = ((i & k) == 0);
          if ((a < b) == desc) { s[i] = b; s[ixj] = a; }
        }
      }
    }
  }
  __syncthreads();
}

// ---- S4: exact per-(b,level) top-1000 by (score desc, idx asc) ----
__global__ __launch_bounds__(SORT_THREADS)
void k_seltop(const u64* __restrict__ sel, const u32* __restrict__ selcnt,
              float* __restrict__ cand_s, u32* __restrict__ cand_t) {
  __shared__ u64 smem[NSORT];
  int g = blockIdx.x;
  int b = g / NLEV, l = g % NLEV;
  u32 m = selcnt[g]; if (m > SELCAP) m = SELCAP;
  for (int i = threadIdx.x; i < NSORT; i += SORT_THREADS)
    smem[i] = (i < (int)m) ? sel[(size_t)g * SELCAP + i] : 0ULL;
  bitonic_desc(smem);
  for (int r = threadIdx.x; r < TOPK; r += SORT_THREADS) {
    u64 key = smem[r];
    u32 bits = (u32)(key >> 32);
    u32 e = ~((u32)key);
    int slot = b * NCAND + l * TOPK + r;
    cand_s[slot] = __uint_as_float(bits);
    cand_t[slot] = ((u32)l << 19) | (e & 0x7FFFFu);
  }
}

// ---- G1: per-image stable sort of 5000 candidates + fused box decode ----
__global__ __launch_bounds__(SORT_THREADS)
void k_gsort(const float* __restrict__ cand_s, const u32* __restrict__ cand_t,
             LevelPtrs lp,
             float* __restrict__ sort_s, u32* __restrict__ sort_t,
             float* __restrict__ sbox, float* __restrict__ slbl) {
  __shared__ u64 smem[NSORT];
  int b = blockIdx.x;
  for (int i = threadIdx.x; i < NSORT; i += SORT_THREADS) {
    u64 key = 0;
    if (i < NCAND) {
      float s = cand_s[b * NCAND + i];
      if (s > SCORE_TH) {
        u32 t = cand_t[b * NCAND + i];
        key = ((u64)__float_as_uint(s) << 32) | (u32)(~t);
      }
    }
    smem[i] = key;
  }
  bitonic_desc(smem);
  // fused decode straight from sorted keys (still in LDS)
  for (int i = threadIdx.x; i < NCAND; i += SORT_THREADS) {
    u64 key = smem[i];
    float bx0 = 0.f, bx1 = 0.f, bx2 = 0.f, bx3 = 0.f, lbl = 0.f;
    if (key) {
      u32 t = ~((u32)key);
      sort_s[b * NCAND + i] = __uint_as_float((u32)(key >> 32));
      sort_t[b * NCAND + i] = t;
      int l = (int)(t >> 19);
      u32 e = t & 0x7FFFFu;
      int c = (int)(e & 7u);
      u32 anc = e >> 3;              // loc*9 + a
      int a = (int)(anc % 9u);
      int loc = (int)(anc / 9u);
      int f = c_f[l];
      int Nloc = f * f;
      const float* rp = lp.reg[l];
      const float* ap = lp.anc[l] + (size_t)anc * 4;
      float r0 = rp[((size_t)b * NREGCH + (a * 4 + 0)) * Nloc + loc];
      float r1 = rp[((size_t)b * NREGCH + (a * 4 + 1)) * Nloc + loc];
      float r2 = rp[((size_t)b * NREGCH + (a * 4 + 2)) * Nloc + loc];
      float r3 = rp[((size_t)b * NREGCH + (a * 4 + 3)) * Nloc + loc];
      float a0 = ap[0], a1 = ap[1], a2 = ap[2], a3 = ap[3];
      float aw = __fsub_rn(a2, a0);
      float ah = __fsub_rn(a3, a1);
      float acx = __fadd_rn(a0, __fmul_rn(0.5f, aw));
      float acy = __fadd_rn(a1, __fmul_rn(0.5f, ah));
      float dw = fminf(r2, BBOX_CLIP_F);
      float dh = fminf(r3, BBOX_CLIP_F);
      float pcx = __fadd_rn(__fmul_rn(r0, aw), acx);
      float pcy = __fadd_rn(__fmul_rn(r1, ah), acy);
      float pw = __fmul_rn(expf(dw), aw);
      float ph = __fmul_rn(expf(dh), ah);
      float hx = __fmul_rn(0.5f, pw);
      float hy = __fmul_rn(0.5f, ph);
      bx0 = fminf(fmaxf(__fsub_rn(pcx, hx), 0.0f), IMGSZ);
      bx1 = fminf(fmaxf(__fsub_rn(pcy, hy), 0.0f), IMGSZ);
      bx2 = fminf(fmaxf(__fadd_rn(pcx, hx), 0.0f), IMGSZ);
      bx3 = fminf(fmaxf(__fadd_rn(pcy, hy), 0.0f), IMGSZ);
      lbl = (float)c;
    } else {
      sort_s[b * NCAND + i] = -1.0f;
      sort_t[b * NCAND + i] = 0xFFFFFFFFu;
    }
    float4 v; v.x = bx0; v.y = bx1; v.z = bx2; v.w = bx3;
    ((float4*)sbox)[b * NCAND + i] = v;
    slbl[b * NCAND + i] = lbl;
  }
}

// IoU > thresh predicate — identical _rn sequence everywhere
__device__ __forceinline__ bool iou_gt(float p0, float p1, float p2, float p3, float pa,
                                       float q0, float q1, float q2, float q3, float qa) {
  float ltx = fmaxf(p0, q0), lty = fmaxf(p1, q1);
  float rx  = fminf(p2, q2), ry  = fminf(p3, q3);
  float ww = fmaxf(__fsub_rn(rx, ltx), 0.0f);
  float hh = fmaxf(__fsub_rn(ry, lty), 0.0f);
  float inter = __fmul_rn(ww, hh);
  float denom = fmaxf(__fsub_rn(__fadd_rn(pa, qa), inter), 1e-7f);
  return __fdiv_rn(inter, denom) > NMS_TH;
}

// ---- G2: wave-parallel group greedy NMS (one wave per image) + fused output ----
__global__ __launch_bounds__(64)
void k_nms(const float* __restrict__ sort_s, const float* __restrict__ sbox,
           const float* __restrict__ slbl, float* __restrict__ out) {
  int b = blockIdx.x;
  int lane = threadIdx.x;           // blockDim = 64 (one wave)
  __shared__ float4 kbox[NDET];     // kept boxes (class-offset space)
  __shared__ float  karea[NDET];
  __shared__ int    kidx[NDET];
  int n = 0;
  bool done = false;
  for (int base = 0; base < NCAND && !done; base += 64) {
    int ci = base + lane;
    float s = (ci < NCAND) ? sort_s[b * NCAND + ci] : -1.0f;
    bool valid = s > 0.0f;
    float4 q = make_float4(0.f, 0.f, 0.f, 0.f);
    float areaq = 0.f;
    if (valid) {
      q = ((const float4*)sbox)[b * NCAND + ci];
      float off = __fmul_rn(slbl[b * NCAND + ci], IMGSZ + 1.0f);
      q.x = __fadd_rn(q.x, off); q.y = __fadd_rn(q.y, off);
      q.z = __fadd_rn(q.z, off); q.w = __fadd_rn(q.w, off);
      areaq = __fmul_rn(__fsub_rn(q.z, q.x), __fsub_rn(q.w, q.y));
    }
    // phase A: parallel pre-test vs existing kept (LDS broadcast reads)
    bool sup = false;
    for (int k = 0; k < n; ++k) {
      float4 p = kbox[k];
      if (iou_gt(p.x, p.y, p.z, p.w, karea[k], q.x, q.y, q.z, q.w, areaq)) sup = true;
    }
    u64 pending = __ballot((int)(valid && !sup));
    // phase B: intra-group suppression rows (r suppresses j>r), pending lanes only
    u64 row = 0;
    u64 m = pending;
    while (m) {
      int j = __builtin_ctzll(m); m &= m - 1;
      float jx0 = __shfl(q.x, j), jy0 = __shfl(q.y, j);
      float jx1 = __shfl(q.z, j), jy1 = __shfl(q.w, j);
      float ja  = __shfl(areaq, j);
      if (j > lane &&
          iou_gt(q.x, q.y, q.z, q.w, areaq, jx0, jy0, jx1, jy1, ja))
        row |= (1ull << j);
    }
    // phase C: wave-uniform serial resolution in greedy (ascending) order
    u64 rem = pending;
    while (rem) {
      int r = __builtin_ctzll(rem);
      rem &= ~(1ull << r);
      float rx0 = __shfl(q.x, r), ry0 = __shfl(q.y, r);
      float rx1 = __shfl(q.z, r), ry1 = __shfl(q.w, r);
      float ra  = __shfl(areaq, r);
      if (lane == 0) {
        kbox[n] = make_float4(rx0, ry0, rx1, ry1);
        karea[n] = ra;
        kidx[n] = base + r;
      }
      ++n;
      if (n == NDET) { done = true; break; }
      u64 rrow = __shfl(row, r);
      rem &= ~rrow;
    }
    if (__any((int)(!valid))) done = true;   // sorted: rest of list invalid
  }
  // fused output: boxes [B,300,4] ++ scores [B,300] ++ labels [B,300]
  for (int k = lane; k < NDET; k += 64) {
    float bx0 = 0.f, bx1 = 0.f, bx2 = 0.f, bx3 = 0.f, sc = 0.f, lb = -1.0f;
    if (k < n) {
      int i = kidx[k];
      float4 v = ((const float4*)sbox)[b * NCAND + i];
      bx0 = v.x; bx1 = v.y; bx2 = v.z; bx3 = v.w;
      sc = sort_s[b * NCAND + i];
      lb = slbl[b * NCAND + i];
    }
    int idx = b * NDET + k;
    out[(size_t)idx * 4 + 0] = bx0;
    out[(size_t)idx * 4 + 1] = bx1;
    out[(size_t)idx * 4 + 2] = bx2;
    out[(size_t)idx * 4 + 3] = bx3;
    out[NB * NDET * 4 + idx] = sc;
    out[NB * NDET * 5 + idx] = lb;
  }
}

extern "C" void kernel_launch(void* const* d_in, const int* in_sizes, int n_in,
                              void* d_out, int out_size, void* d_ws, size_t ws_size,
                              hipStream_t stream) {
  const float* cls[NLEV]; const float* reg[NLEV]; const float* anc[NLEV];
  // dict order (cls,reg,anc per level) vs signature order (all cls, all reg, all anc)
  bool dict_order = (n_in >= 2) && (in_sizes[1] == 4 * NREGCH * 64 * 64);
  for (int l = 0; l < NLEV; ++l) {
    if (dict_order) {
      cls[l] = (const float*)d_in[3 * l + 0];
      reg[l] = (const float*)d_in[3 * l + 1];
      anc[l] = (const float*)d_in[3 * l + 2];
    } else {
      cls[l] = (const float*)d_in[l];
      reg[l] = (const float*)d_in[NLEV + l];
      anc[l] = (const float*)d_in[2 * NLEV + l];
    }
  }

  char* ws = (char*)d_ws;
  size_t off = 0;
  auto alloc = [&](size_t bytes) -> void* {
    void* p = ws + off;
    off = (off + bytes + 255) & ~(size_t)255;
    return p;
  };
  u32*   selcnt = (u32*)  alloc(20 * 4);
  u32*   hist   = (u32*)  alloc(20ULL * NBINS * 4);
  int*   cutbin = (int*)  alloc(20 * 4);
  u64*   sel    = (u64*)  alloc(20ULL * SELCAP * 8);
  float* cand_s = (float*)alloc((size_t)NB * NCAND * 4);
  u32*   cand_t = (u32*)  alloc((size_t)NB * NCAND * 4);
  float* sort_s = (float*)alloc((size_t)NB * NCAND * 4);
  u32*   sort_t = (u32*)  alloc((size_t)NB * NCAND * 4);
  float* sbox   = (float*)alloc((size_t)NB * NCAND * 16);
  float* slbl   = (float*)alloc((size_t)NB * NCAND * 4);
  (void)ws_size; (void)out_size;

  // zero selcnt + hist (contiguous from ws base through end of hist)
  size_t zero_bytes = (size_t)((char*)cutbin - (char*)selcnt);
  hipMemsetAsync(selcnt, 0, zero_bytes, stream);

  ClsPtrs cp;
  for (int l = 0; l < NLEV; ++l) cp.p[l] = cls[l];

  k_hist<<<NB * NCHUNK_IMG, 256, 0, stream>>>(cp, hist);
  k_cut<<<20, 256, 0, stream>>>(hist, cutbin);
  k_compact<<<NB * NCHUNK_IMG, 256, 0, stream>>>(cp, cutbin, selcnt, sel);
  k_seltop<<<20, SORT_THREADS, 0, stream>>>(sel, selcnt, cand_s, cand_t);

  LevelPtrs lp;
  for (int l = 0; l < NLEV; ++l) { lp.reg[l] = reg[l]; lp.anc[l] = anc[l]; }
  k_gsort<<<NB, SORT_THREADS, 0, stream>>>(cand_s, cand_t, lp, sort_s, sort_t, sbox, slbl);
  k_nms<<<NB, 64, 0, stream>>>(sort_s, sbox, slbl, (float*)d_out);
}

// Round 5
// 403.620 us; speedup vs baseline: 3.2615x; 1.5748x over previous
//
#include <hip/hip_runtime.h>
#include <stdint.h>
#include <stddef.h>

typedef unsigned int u32;
typedef unsigned long long u64;

#define NB 4
#define NLEV 5
#define NCH 72      // A*C = 9*8
#define NREGCH 36   // A*4
#define TOPK 1000
#define NCAND 5000  // NLEV*TOPK
#define NDET 300
#define NBINS 4096        // sigmoid in (0,1]: bits>>18 <= 4064
#define SELCAP 4096       // m (selected per group) measured ~1100-1800; 4096 is 2x margin
#define CHUNK 8192        // elements per histogram/compact block
#define NCHUNK_IMG 50     // 36+9+3+1+1 chunks per image across levels
#define IMGSZ 512.0f
#define SCORE_TH 0.05f
#define NMS_TH 0.5f
#define BBOX_CLIP_F 4.135166556742356f

__constant__ int c_f[NLEV] = {64, 32, 16, 8, 4};

// ---- XLA-CPU-style sigmoid: logistic(x) = 0.5 + 0.5*tanh(0.5*x), fast-tanh poly, no FMA ----
__device__ __forceinline__ float xla_tanh_f32(float x) {
  float ax = fabsf(x);
  float xc = fminf(fmaxf(x, -7.90531110763549805f), 7.90531110763549805f);
  float x2 = __fmul_rn(xc, xc);
  float p = -2.76076847742355e-16f;
  p = __fadd_rn(__fmul_rn(x2, p), 2.00018790482477e-13f);
  p = __fadd_rn(__fmul_rn(x2, p), -8.60467152213735e-11f);
  p = __fadd_rn(__fmul_rn(x2, p), 5.12229709037114e-08f);
  p = __fadd_rn(__fmul_rn(x2, p), 1.48572235717979e-05f);
  p = __fadd_rn(__fmul_rn(x2, p), 6.37261928875436e-04f);
  p = __fadd_rn(__fmul_rn(x2, p), 4.89352455891786e-03f);
  float num = __fmul_rn(xc, p);
  float q = 1.19825839466702e-06f;
  q = __fadd_rn(__fmul_rn(x2, q), 1.18534705686654e-04f);
  q = __fadd_rn(__fmul_rn(x2, q), 2.26843463243900e-03f);
  q = __fadd_rn(__fmul_rn(x2, q), 4.89352518554385e-03f);
  float r = __fdiv_rn(num, q);
  return (ax < 0.0004f) ? x : r;
}
__device__ __forceinline__ float sigmoid_ref(float x) {
  return __fadd_rn(0.5f, __fmul_rn(0.5f, xla_tanh_f32(__fmul_rn(0.5f, x))));
}

struct ClsPtrs { const float* p[NLEV]; };
struct LevelPtrs { const float* reg[NLEV]; const float* anc[NLEV]; };

// block → (b, level, chunk) mapping for the fused hist/compact grids
__device__ __forceinline__ void chunk_map(int bid, int& b, int& level, int& chunk) {
  b = bid / NCHUNK_IMG;
  int cid = bid % NCHUNK_IMG;
  if      (cid < 36) { level = 0; chunk = cid; }
  else if (cid < 45) { level = 1; chunk = cid - 36; }
  else if (cid < 48) { level = 2; chunk = cid - 45; }
  else if (cid < 49) { level = 3; chunk = cid - 48; }
  else               { level = 4; chunk = cid - 49; }
}
__constant__ int c_Nloc[NLEV] = {4096, 1024, 256, 64, 16};
__constant__ int c_lg2[NLEV]  = {12, 10, 8, 6, 4};

// ---- S1: fused LDS-privatized histogram of sigmoid bits (bits>>18), per (b,level) ----
__global__ __launch_bounds__(256)
void k_hist(ClsPtrs cp, u32* __restrict__ hist) {
  int b, level, chunk;
  chunk_map(blockIdx.x, b, level, chunk);
  int Nloc = c_Nloc[level];
  int Nsc = Nloc * NCH;
  __shared__ u32 lh[NBINS];
  for (int i = threadIdx.x; i < NBINS; i += 256) lh[i] = 0;
  __syncthreads();
  const float* cls = cp.p[level] + (size_t)b * Nsc;   // [72][Nloc] flat
  int base = chunk * CHUNK;
  int end = base + CHUNK; if (end > Nsc) end = Nsc;
  for (int i = base + threadIdx.x; i < end; i += 256) {
    float s = sigmoid_ref(cls[i]);
    atomicAdd(&lh[__float_as_uint(s) >> 18], 1u);
  }
  __syncthreads();
  u32* gh = hist + (size_t)(b * NLEV + level) * NBINS;
  for (int i = threadIdx.x; i < NBINS; i += 256) {
    u32 v = lh[i];
    if (v) atomicAdd(&gh[i], v);
  }
}

// ---- S2: cut bin per (b,level): highest-from-top bin where cum >= TOPK ----
__global__ void k_cut(const u32* __restrict__ hist, int* __restrict__ cutbin) {
  int g = blockIdx.x;
  const u32* h = hist + (size_t)g * NBINS;
  __shared__ u32 part[256];
  int t = threadIdx.x;
  u32 s = 0;
  for (int i = 0; i < 16; ++i) s += h[t * 16 + i];
  part[t] = s;
  __syncthreads();
  if (t == 0) {
    u32 c = 0; int T = 0; bool found = false;
    for (int ch = 255; ch >= 0 && !found; --ch) {
      if (c + part[ch] >= TOPK) {
        u32 cc = c;
        for (int bin = ch * 16 + 15; bin >= ch * 16; --bin) {
          cc += h[bin];
          if (cc >= TOPK) { T = bin; found = true; break; }
        }
      } else c += part[ch];
    }
    cutbin[g] = found ? T : 0;
  }
}

// ---- S3: fused compact of elements with bin >= cut ----
__global__ __launch_bounds__(256)
void k_compact(ClsPtrs cp, const int* __restrict__ cutbin,
               u32* __restrict__ selcnt, u64* __restrict__ sel) {
  int b, level, chunk;
  chunk_map(blockIdx.x, b, level, chunk);
  int Nloc = c_Nloc[level];
  int lg2 = c_lg2[level];
  int Nsc = Nloc * NCH;
  int g = b * NLEV + level;
  int cut = cutbin[g];
  const float* cls = cp.p[level] + (size_t)b * Nsc;
  int base = chunk * CHUNK;
  int end = base + CHUNK; if (end > Nsc) end = Nsc;
  for (int i = base + threadIdx.x; i < end; i += 256) {
    float s = sigmoid_ref(cls[i]);
    u32 bits = __float_as_uint(s);
    if ((int)(bits >> 18) >= cut) {
      u32 pos = atomicAdd(&selcnt[g], 1u);
      if (pos < SELCAP) {
        int ch = i >> lg2;
        int loc = i & (Nloc - 1);
        u32 e = (u32)(loc * NCH + ch);   // flat score index ((y*f+x)*9+a)*8+c
        sel[(size_t)g * SELCAP + pos] = ((u64)bits << 32) | (u32)(~e);
      }
    }
  }
}

// ---- S4: exact per-(b,level) top-1000 by rank = count of strictly-greater keys ----
// Keys unique (idx embedded) => rank is an exact stable permutation; output is
// independent of the nondeterministic compaction order.
__global__ __launch_bounds__(1024)
void k_seltop(const u64* __restrict__ sel, const u32* __restrict__ selcnt,
              float* __restrict__ cand_s, u32* __restrict__ cand_t) {
  __shared__ u64 keys[SELCAP];   // 32 KB
  int g = blockIdx.x;
  int b = g / NLEV, l = g % NLEV;
  u32 m = selcnt[g]; if (m > SELCAP) m = SELCAP;
  for (u32 i = threadIdx.x; i < m; i += 1024) keys[i] = sel[(size_t)g * SELCAP + i];
  __syncthreads();
  int obase = b * NCAND + l * TOPK;
  for (u32 i = threadIdx.x; i < m; i += 1024) {
    u64 k0 = keys[i];
    u32 r = 0;
    for (u32 j = 0; j < m; ++j) r += (keys[j] > k0) ? 1u : 0u;   // LDS broadcast scan
    if (r < TOPK) {
      cand_s[obase + r] = __uint_as_float((u32)(k0 >> 32));
      u32 e = ~((u32)k0);
      cand_t[obase + r] = ((u32)l << 19) | (e & 0x7FFFFu);
    }
  }
  // deterministic fill for (impossible-in-practice) m < TOPK + poison safety
  for (u32 r = m + threadIdx.x; r < TOPK; r += 1024) {
    cand_s[obase + r] = -1.0f;
    cand_t[obase + r] = ((u32)l << 19) | r;
  }
}

// ---- G1: 5-way merge by rank (lists already sorted desc by the global key),
//          fused with box decode. Replaces the 8192-key bitonic sort. ----
__global__ __launch_bounds__(1024)
void k_merge(const float* __restrict__ cand_s, const u32* __restrict__ cand_t,
             LevelPtrs lp,
             float* __restrict__ sort_s, u32* __restrict__ sort_t,
             float* __restrict__ sbox, float* __restrict__ slbl) {
  __shared__ u64 keys[NCAND];   // 40 KB
  int b = blockIdx.x;
  for (int i = threadIdx.x; i < NCAND; i += 1024) {
    float s = cand_s[b * NCAND + i];
    u32 t = cand_t[b * NCAND + i];
    u32 hi = (s > SCORE_TH) ? __float_as_uint(s) : 0u;  // invalid -> high word 0 (sorts last)
    keys[i] = ((u64)hi << 32) | (u32)(~t);
  }
  __syncthreads();
  for (int i = threadIdx.x; i < NCAND; i += 1024) {
    u64 k0 = keys[i];
    int l = i / TOPK;
    int rank = i - l * TOPK;                 // own list: all earlier entries are greater
    for (int L = 0; L < NLEV; ++L) {
      if (L == l) continue;
      const u64* A = keys + L * TOPK;        // desc-sorted, unique keys
      int lo = 0, hi2 = TOPK;                // count of A[j] > k0
      while (lo < hi2) { int mid = (lo + hi2) >> 1; if (A[mid] > k0) lo = mid + 1; else hi2 = mid; }
      rank += lo;
    }
    // scatter + fused decode
    u32 t = ~((u32)k0);
    u32 hi = (u32)(k0 >> 32);
    float bx0 = 0.f, bx1 = 0.f, bx2 = 0.f, bx3 = 0.f, lbl = 0.f;
    if (hi) {
      sort_s[b * NCAND + rank] = __uint_as_float(hi);
      sort_t[b * NCAND + rank] = t;
      int lv = (int)(t >> 19);
      u32 e = t & 0x7FFFFu;
      int c = (int)(e & 7u);
      u32 anc = e >> 3;              // loc*9 + a
      int a = (int)(anc % 9u);
      int loc = (int)(anc / 9u);
      int f = c_f[lv];
      int Nloc = f * f;
      const float* rp = lp.reg[lv];
      const float* ap = lp.anc[lv] + (size_t)anc * 4;
      float r0 = rp[((size_t)b * NREGCH + (a * 4 + 0)) * Nloc + loc];
      float r1 = rp[((size_t)b * NREGCH + (a * 4 + 1)) * Nloc + loc];
      float r2 = rp[((size_t)b * NREGCH + (a * 4 + 2)) * Nloc + loc];
      float r3 = rp[((size_t)b * NREGCH + (a * 4 + 3)) * Nloc + loc];
      float a0 = ap[0], a1 = ap[1], a2 = ap[2], a3 = ap[3];
      float aw = __fsub_rn(a2, a0);
      float ah = __fsub_rn(a3, a1);
      float acx = __fadd_rn(a0, __fmul_rn(0.5f, aw));
      float acy = __fadd_rn(a1, __fmul_rn(0.5f, ah));
      float dw = fminf(r2, BBOX_CLIP_F);
      float dh = fminf(r3, BBOX_CLIP_F);
      float pcx = __fadd_rn(__fmul_rn(r0, aw), acx);
      float pcy = __fadd_rn(__fmul_rn(r1, ah), acy);
      float pw = __fmul_rn(expf(dw), aw);
      float ph = __fmul_rn(expf(dh), ah);
      float hx = __fmul_rn(0.5f, pw);
      float hy = __fmul_rn(0.5f, ph);
      bx0 = fminf(fmaxf(__fsub_rn(pcx, hx), 0.0f), IMGSZ);
      bx1 = fminf(fmaxf(__fsub_rn(pcy, hy), 0.0f), IMGSZ);
      bx2 = fminf(fmaxf(__fadd_rn(pcx, hx), 0.0f), IMGSZ);
      bx3 = fminf(fmaxf(__fadd_rn(pcy, hy), 0.0f), IMGSZ);
      lbl = (float)c;
    } else {
      sort_s[b * NCAND + rank] = -1.0f;
      sort_t[b * NCAND + rank] = t;
    }
    float4 v; v.x = bx0; v.y = bx1; v.z = bx2; v.w = bx3;
    ((float4*)sbox)[b * NCAND + rank] = v;
    slbl[b * NCAND + rank] = lbl;
  }
}

// IoU > thresh predicate — identical _rn sequence everywhere
__device__ __forceinline__ bool iou_gt(float p0, float p1, float p2, float p3, float pa,
                                       float q0, float q1, float q2, float q3, float qa) {
  float ltx = fmaxf(p0, q0), lty = fmaxf(p1, q1);
  float rx  = fminf(p2, q2), ry  = fminf(p3, q3);
  float ww = fmaxf(__fsub_rn(rx, ltx), 0.0f);
  float hh = fmaxf(__fsub_rn(ry, lty), 0.0f);
  float inter = __fmul_rn(ww, hh);
  float denom = fmaxf(__fsub_rn(__fadd_rn(pa, qa), inter), 1e-7f);
  return __fdiv_rn(inter, denom) > NMS_TH;
}

// ---- G2: wave-parallel group greedy NMS (one wave per image) + fused output ----
__global__ __launch_bounds__(64)
void k_nms(const float* __restrict__ sort_s, const float* __restrict__ sbox,
           const float* __restrict__ slbl, float* __restrict__ out) {
  int b = blockIdx.x;
  int lane = threadIdx.x;           // blockDim = 64 (one wave)
  __shared__ float4 kbox[NDET];     // kept boxes (class-offset space)
  __shared__ float  karea[NDET];
  __shared__ int    kidx[NDET];
  int n = 0;
  bool done = false;
  for (int base = 0; base < NCAND && !done; base += 64) {
    int ci = base + lane;
    float s = (ci < NCAND) ? sort_s[b * NCAND + ci] : -1.0f;
    bool valid = s > 0.0f;
    float4 q = make_float4(0.f, 0.f, 0.f, 0.f);
    float areaq = 0.f;
    if (valid) {
      q = ((const float4*)sbox)[b * NCAND + ci];
      float off = __fmul_rn(slbl[b * NCAND + ci], IMGSZ + 1.0f);
      q.x = __fadd_rn(q.x, off); q.y = __fadd_rn(q.y, off);
      q.z = __fadd_rn(q.z, off); q.w = __fadd_rn(q.w, off);
      areaq = __fmul_rn(__fsub_rn(q.z, q.x), __fsub_rn(q.w, q.y));
    }
    // phase A: parallel pre-test vs existing kept (LDS broadcast reads)
    bool sup = false;
    for (int k = 0; k < n; ++k) {
      float4 p = kbox[k];
      if (iou_gt(p.x, p.y, p.z, p.w, karea[k], q.x, q.y, q.z, q.w, areaq)) sup = true;
    }
    u64 pending = __ballot((int)(valid && !sup));
    // phase B: intra-group suppression rows (r suppresses j>r), pending lanes only
    u64 row = 0;
    u64 m = pending;
    while (m) {
      int j = __builtin_ctzll(m); m &= m - 1;
      float jx0 = __shfl(q.x, j), jy0 = __shfl(q.y, j);
      float jx1 = __shfl(q.z, j), jy1 = __shfl(q.w, j);
      float ja  = __shfl(areaq, j);
      if (j > lane &&
          iou_gt(q.x, q.y, q.z, q.w, areaq, jx0, jy0, jx1, jy1, ja))
        row |= (1ull << j);
    }
    // phase C: wave-uniform serial resolution in greedy (ascending) order
    u64 rem = pending;
    while (rem) {
      int r = __builtin_ctzll(rem);
      rem &= ~(1ull << r);
      float rx0 = __shfl(q.x, r), ry0 = __shfl(q.y, r);
      float rx1 = __shfl(q.z, r), ry1 = __shfl(q.w, r);
      float ra  = __shfl(areaq, r);
      if (lane == 0) {
        kbox[n] = make_float4(rx0, ry0, rx1, ry1);
        karea[n] = ra;
        kidx[n] = base + r;
      }
      ++n;
      if (n == NDET) { done = true; break; }
      u64 rrow = __shfl(row, r);
      rem &= ~rrow;
    }
    if (__any((int)(!valid))) done = true;   // sorted: rest of list invalid
  }
  // fused output: boxes [B,300,4] ++ scores [B,300] ++ labels [B,300]
  for (int k = lane; k < NDET; k += 64) {
    float bx0 = 0.f, bx1 = 0.f, bx2 = 0.f, bx3 = 0.f, sc = 0.f, lb = -1.0f;
    if (k < n) {
      int i = kidx[k];
      float4 v = ((const float4*)sbox)[b * NCAND + i];
      bx0 = v.x; bx1 = v.y; bx2 = v.z; bx3 = v.w;
      sc = sort_s[b * NCAND + i];
      lb = slbl[b * NCAND + i];
    }
    int idx = b * NDET + k;
    out[(size_t)idx * 4 + 0] = bx0;
    out[(size_t)idx * 4 + 1] = bx1;
    out[(size_t)idx * 4 + 2] = bx2;
    out[(size_t)idx * 4 + 3] = bx3;
    out[NB * NDET * 4 + idx] = sc;
    out[NB * NDET * 5 + idx] = lb;
  }
}

extern "C" void kernel_launch(void* const* d_in, const int* in_sizes, int n_in,
                              void* d_out, int out_size, void* d_ws, size_t ws_size,
                              hipStream_t stream) {
  const float* cls[NLEV]; const float* reg[NLEV]; const float* anc[NLEV];
  // dict order (cls,reg,anc per level) vs signature order (all cls, all reg, all anc)
  bool dict_order = (n_in >= 2) && (in_sizes[1] == 4 * NREGCH * 64 * 64);
  for (int l = 0; l < NLEV; ++l) {
    if (dict_order) {
      cls[l] = (const float*)d_in[3 * l + 0];
      reg[l] = (const float*)d_in[3 * l + 1];
      anc[l] = (const float*)d_in[3 * l + 2];
    } else {
      cls[l] = (const float*)d_in[l];
      reg[l] = (const float*)d_in[NLEV + l];
      anc[l] = (const float*)d_in[2 * NLEV + l];
    }
  }

  char* ws = (char*)d_ws;
  size_t off = 0;
  auto alloc = [&](size_t bytes) -> void* {
    void* p = ws + off;
    off = (off + bytes + 255) & ~(size_t)255;
    return p;
  };
  u32*   selcnt = (u32*)  alloc(20 * 4);
  u32*   hist   = (u32*)  alloc(20ULL * NBINS * 4);
  int*   cutbin = (int*)  alloc(20 * 4);
  u64*   sel    = (u64*)  alloc(20ULL * SELCAP * 8);
  float* cand_s = (float*)alloc((size_t)NB * NCAND * 4);
  u32*   cand_t = (u32*)  alloc((size_t)NB * NCAND * 4);
  float* sort_s = (float*)alloc((size_t)NB * NCAND * 4);
  u32*   sort_t = (u32*)  alloc((size_t)NB * NCAND * 4);
  float* sbox   = (float*)alloc((size_t)NB * NCAND * 16);
  float* slbl   = (float*)alloc((size_t)NB * NCAND * 4);
  (void)ws_size; (void)out_size;

  // zero selcnt + hist (contiguous from ws base through end of hist)
  size_t zero_bytes = (size_t)((char*)cutbin - (char*)selcnt);
  hipMemsetAsync(selcnt, 0, zero_bytes, stream);

  ClsPtrs cp;
  for (int l = 0; l < NLEV; ++l) cp.p[l] = cls[l];

  k_hist<<<NB * NCHUNK_IMG, 256, 0, stream>>>(cp, hist);
  k_cut<<<20, 256, 0, stream>>>(hist, cutbin);
  k_compact<<<NB * NCHUNK_IMG, 256, 0, stream>>>(cp, cutbin, selcnt, sel);
  k_seltop<<<20, 1024, 0, stream>>>(sel, selcnt, cand_s, cand_t);

  LevelPtrs lp;
  for (int l = 0; l < NLEV; ++l) { lp.reg[l] = reg[l]; lp.anc[l] = anc[l]; }
  k_merge<<<NB, 1024, 0, stream>>>(cand_s, cand_t, lp, sort_s, sort_t, sbox, slbl);
  k_nms<<<NB, 64, 0, stream>>>(sort_s, sbox, slbl, (float*)d_out);
}

// Round 6
// 349.539 us; speedup vs baseline: 3.7661x; 1.1547x over previous
//
#include <hip/hip_runtime.h>
#include <stdint.h>
#include <stddef.h>

typedef unsigned int u32;
typedef unsigned long long u64;

#define NB 4
#define NLEV 5
#define NCH 72      // A*C = 9*8
#define NREGCH 36   // A*4
#define TOPK 1000
#define NCAND 5000  // NLEV*TOPK
#define NDET 300
#define NBINS 4096        // sigmoid in (0,1]: bits>>18 <= 4064
#define SELCAP 4096       // m (selected per group) measured ~1100-1800; 4096 is 2x margin
#define CHUNK 8192        // elements per histogram/compact block
#define NCHUNK_IMG 50     // 36+9+3+1+1 chunks per image across levels
#define IMGSZ 512.0f
#define SCORE_TH 0.05f
#define NMS_TH 0.5f
#define BBOX_CLIP_F 4.135166556742356f

__constant__ int c_f[NLEV] = {64, 32, 16, 8, 4};

// ---- XLA-CPU-style sigmoid: logistic(x) = 0.5 + 0.5*tanh(0.5*x), fast-tanh poly, no FMA ----
__device__ __forceinline__ float xla_tanh_f32(float x) {
  float ax = fabsf(x);
  float xc = fminf(fmaxf(x, -7.90531110763549805f), 7.90531110763549805f);
  float x2 = __fmul_rn(xc, xc);
  float p = -2.76076847742355e-16f;
  p = __fadd_rn(__fmul_rn(x2, p), 2.00018790482477e-13f);
  p = __fadd_rn(__fmul_rn(x2, p), -8.60467152213735e-11f);
  p = __fadd_rn(__fmul_rn(x2, p), 5.12229709037114e-08f);
  p = __fadd_rn(__fmul_rn(x2, p), 1.48572235717979e-05f);
  p = __fadd_rn(__fmul_rn(x2, p), 6.37261928875436e-04f);
  p = __fadd_rn(__fmul_rn(x2, p), 4.89352455891786e-03f);
  float num = __fmul_rn(xc, p);
  float q = 1.19825839466702e-06f;
  q = __fadd_rn(__fmul_rn(x2, q), 1.18534705686654e-04f);
  q = __fadd_rn(__fmul_rn(x2, q), 2.26843463243900e-03f);
  q = __fadd_rn(__fmul_rn(x2, q), 4.89352518554385e-03f);
  float r = __fdiv_rn(num, q);
  return (ax < 0.0004f) ? x : r;
}
__device__ __forceinline__ float sigmoid_ref(float x) {
  return __fadd_rn(0.5f, __fmul_rn(0.5f, xla_tanh_f32(__fmul_rn(0.5f, x))));
}

struct ClsPtrs { const float* p[NLEV]; };
struct LevelPtrs { const float* reg[NLEV]; const float* anc[NLEV]; };

// block → (b, level, chunk) mapping for the fused hist/compact grids
__device__ __forceinline__ void chunk_map(int bid, int& b, int& level, int& chunk) {
  b = bid / NCHUNK_IMG;
  int cid = bid % NCHUNK_IMG;
  if      (cid < 36) { level = 0; chunk = cid; }
  else if (cid < 45) { level = 1; chunk = cid - 36; }
  else if (cid < 48) { level = 2; chunk = cid - 45; }
  else if (cid < 49) { level = 3; chunk = cid - 48; }
  else               { level = 4; chunk = cid - 49; }
}
__constant__ int c_Nloc[NLEV] = {4096, 1024, 256, 64, 16};
__constant__ int c_lg2[NLEV]  = {12, 10, 8, 6, 4};

// ---- S1: fused LDS-privatized histogram of sigmoid bits (bits>>18), per (b,level) ----
__global__ __launch_bounds__(256)
void k_hist(ClsPtrs cp, u32* __restrict__ hist) {
  int b, level, chunk;
  chunk_map(blockIdx.x, b, level, chunk);
  int Nloc = c_Nloc[level];
  int Nsc = Nloc * NCH;
  __shared__ u32 lh[NBINS];
  for (int i = threadIdx.x; i < NBINS; i += 256) lh[i] = 0;
  __syncthreads();
  const float* cls = cp.p[level] + (size_t)b * Nsc;   // [72][Nloc] flat
  int base = chunk * CHUNK;
  int end = base + CHUNK; if (end > Nsc) end = Nsc;
  for (int i = base + threadIdx.x; i < end; i += 256) {
    float s = sigmoid_ref(cls[i]);
    atomicAdd(&lh[__float_as_uint(s) >> 18], 1u);
  }
  __syncthreads();
  u32* gh = hist + (size_t)(b * NLEV + level) * NBINS;
  for (int i = threadIdx.x; i < NBINS; i += 256) {
    u32 v = lh[i];
    if (v) atomicAdd(&gh[i], v);
  }
}

// ---- S2: cut bin per (b,level): highest-from-top bin where cum >= TOPK ----
__global__ void k_cut(const u32* __restrict__ hist, int* __restrict__ cutbin) {
  int g = blockIdx.x;
  const u32* h = hist + (size_t)g * NBINS;
  __shared__ u32 part[256];
  int t = threadIdx.x;
  u32 s = 0;
  for (int i = 0; i < 16; ++i) s += h[t * 16 + i];
  part[t] = s;
  __syncthreads();
  if (t == 0) {
    u32 c = 0; int T = 0; bool found = false;
    for (int ch = 255; ch >= 0 && !found; --ch) {
      if (c + part[ch] >= TOPK) {
        u32 cc = c;
        for (int bin = ch * 16 + 15; bin >= ch * 16; --bin) {
          cc += h[bin];
          if (cc >= TOPK) { T = bin; found = true; break; }
        }
      } else c += part[ch];
    }
    cutbin[g] = found ? T : 0;
  }
}

// ---- S3: fused compact of elements with bin >= cut ----
__global__ __launch_bounds__(256)
void k_compact(ClsPtrs cp, const int* __restrict__ cutbin,
               u32* __restrict__ selcnt, u64* __restrict__ sel) {
  int b, level, chunk;
  chunk_map(blockIdx.x, b, level, chunk);
  int Nloc = c_Nloc[level];
  int lg2 = c_lg2[level];
  int Nsc = Nloc * NCH;
  int g = b * NLEV + level;
  int cut = cutbin[g];
  const float* cls = cp.p[level] + (size_t)b * Nsc;
  int base = chunk * CHUNK;
  int end = base + CHUNK; if (end > Nsc) end = Nsc;
  for (int i = base + threadIdx.x; i < end; i += 256) {
    float s = sigmoid_ref(cls[i]);
    u32 bits = __float_as_uint(s);
    if ((int)(bits >> 18) >= cut) {
      u32 pos = atomicAdd(&selcnt[g], 1u);
      if (pos < SELCAP) {
        int ch = i >> lg2;
        int loc = i & (Nloc - 1);
        u32 e = (u32)(loc * NCH + ch);   // flat score index ((y*f+x)*9+a)*8+c
        sel[(size_t)g * SELCAP + pos] = ((u64)bits << 32) | (u32)(~e);
      }
    }
  }
}

// ---- S4: exact per-(b,level) top-1000 by rank = count of strictly-greater keys ----
__global__ __launch_bounds__(1024)
void k_seltop(const u64* __restrict__ sel, const u32* __restrict__ selcnt,
              float* __restrict__ cand_s, u32* __restrict__ cand_t) {
  __shared__ u64 keys[SELCAP];   // 32 KB
  int g = blockIdx.x;
  int b = g / NLEV, l = g % NLEV;
  u32 m = selcnt[g]; if (m > SELCAP) m = SELCAP;
  for (u32 i = threadIdx.x; i < m; i += 1024) keys[i] = sel[(size_t)g * SELCAP + i];
  __syncthreads();
  int obase = b * NCAND + l * TOPK;
  for (u32 i = threadIdx.x; i < m; i += 1024) {
    u64 k0 = keys[i];
    u32 r = 0;
    for (u32 j = 0; j < m; ++j) r += (keys[j] > k0) ? 1u : 0u;   // LDS broadcast scan
    if (r < TOPK) {
      cand_s[obase + r] = __uint_as_float((u32)(k0 >> 32));
      u32 e = ~((u32)k0);
      cand_t[obase + r] = ((u32)l << 19) | (e & 0x7FFFFu);
    }
  }
  // deterministic fill for (impossible-in-practice) m < TOPK + poison safety
  for (u32 r = m + threadIdx.x; r < TOPK; r += 1024) {
    cand_s[obase + r] = -1.0f;
    cand_t[obase + r] = ((u32)l << 19) | r;
  }
}

// ---- G1: 5-way merge by rank (lists already sorted desc by the global key),
//          fused with box decode. ----
__global__ __launch_bounds__(1024)
void k_merge(const float* __restrict__ cand_s, const u32* __restrict__ cand_t,
             LevelPtrs lp,
             float* __restrict__ sort_s, u32* __restrict__ sort_t,
             float* __restrict__ sbox, float* __restrict__ slbl) {
  __shared__ u64 keys[NCAND];   // 40 KB
  int b = blockIdx.x;
  for (int i = threadIdx.x; i < NCAND; i += 1024) {
    float s = cand_s[b * NCAND + i];
    u32 t = cand_t[b * NCAND + i];
    u32 hi = (s > SCORE_TH) ? __float_as_uint(s) : 0u;  // invalid -> high word 0 (sorts last)
    keys[i] = ((u64)hi << 32) | (u32)(~t);
  }
  __syncthreads();
  for (int i = threadIdx.x; i < NCAND; i += 1024) {
    u64 k0 = keys[i];
    int l = i / TOPK;
    int rank = i - l * TOPK;                 // own list: all earlier entries are greater
    for (int L = 0; L < NLEV; ++L) {
      if (L == l) continue;
      const u64* A = keys + L * TOPK;        // desc-sorted, unique keys
      int lo = 0, hi2 = TOPK;                // count of A[j] > k0
      while (lo < hi2) { int mid = (lo + hi2) >> 1; if (A[mid] > k0) lo = mid + 1; else hi2 = mid; }
      rank += lo;
    }
    // scatter + fused decode
    u32 t = ~((u32)k0);
    u32 hi = (u32)(k0 >> 32);
    float bx0 = 0.f, bx1 = 0.f, bx2 = 0.f, bx3 = 0.f, lbl = 0.f;
    if (hi) {
      sort_s[b * NCAND + rank] = __uint_as_float(hi);
      sort_t[b * NCAND + rank] = t;
      int lv = (int)(t >> 19);
      u32 e = t & 0x7FFFFu;
      int c = (int)(e & 7u);
      u32 anc = e >> 3;              // loc*9 + a
      int a = (int)(anc % 9u);
      int loc = (int)(anc / 9u);
      int f = c_f[lv];
      int Nloc = f * f;
      const float* rp = lp.reg[lv];
      const float* ap = lp.anc[lv] + (size_t)anc * 4;
      float r0 = rp[((size_t)b * NREGCH + (a * 4 + 0)) * Nloc + loc];
      float r1 = rp[((size_t)b * NREGCH + (a * 4 + 1)) * Nloc + loc];
      float r2 = rp[((size_t)b * NREGCH + (a * 4 + 2)) * Nloc + loc];
      float r3 = rp[((size_t)b * NREGCH + (a * 4 + 3)) * Nloc + loc];
      float a0 = ap[0], a1 = ap[1], a2 = ap[2], a3 = ap[3];
      float aw = __fsub_rn(a2, a0);
      float ah = __fsub_rn(a3, a1);
      float acx = __fadd_rn(a0, __fmul_rn(0.5f, aw));
      float acy = __fadd_rn(a1, __fmul_rn(0.5f, ah));
      float dw = fminf(r2, BBOX_CLIP_F);
      float dh = fminf(r3, BBOX_CLIP_F);
      float pcx = __fadd_rn(__fmul_rn(r0, aw), acx);
      float pcy = __fadd_rn(__fmul_rn(r1, ah), acy);
      float pw = __fmul_rn(expf(dw), aw);
      float ph = __fmul_rn(expf(dh), ah);
      float hx = __fmul_rn(0.5f, pw);
      float hy = __fmul_rn(0.5f, ph);
      bx0 = fminf(fmaxf(__fsub_rn(pcx, hx), 0.0f), IMGSZ);
      bx1 = fminf(fmaxf(__fsub_rn(pcy, hy), 0.0f), IMGSZ);
      bx2 = fminf(fmaxf(__fadd_rn(pcx, hx), 0.0f), IMGSZ);
      bx3 = fminf(fmaxf(__fadd_rn(pcy, hy), 0.0f), IMGSZ);
      lbl = (float)c;
    } else {
      sort_s[b * NCAND + rank] = -1.0f;
      sort_t[b * NCAND + rank] = t;
    }
    float4 v; v.x = bx0; v.y = bx1; v.z = bx2; v.w = bx3;
    ((float4*)sbox)[b * NCAND + rank] = v;
    slbl[b * NCAND + rank] = lbl;
  }
}

// IoU > thresh predicate — identical _rn sequence everywhere
__device__ __forceinline__ bool iou_gt(float p0, float p1, float p2, float p3, float pa,
                                       float q0, float q1, float q2, float q3, float qa) {
  float ltx = fmaxf(p0, q0), lty = fmaxf(p1, q1);
  float rx  = fminf(p2, q2), ry  = fminf(p3, q3);
  float ww = fmaxf(__fsub_rn(rx, ltx), 0.0f);
  float hh = fmaxf(__fsub_rn(ry, lty), 0.0f);
  float inter = __fmul_rn(ww, hh);
  float denom = fmaxf(__fsub_rn(__fadd_rn(pa, qa), inter), 1e-7f);
  return __fdiv_rn(inter, denom) > NMS_TH;
}
__device__ __forceinline__ bool iou_gt4(float4 p, float pa, float4 q, float qa) {
  return iou_gt(p.x, p.y, p.z, p.w, pa, q.x, q.y, q.z, q.w, qa);
}

// ---- G2: wave-parallel group greedy NMS, latency-batched (one wave per image) ----
__global__ __launch_bounds__(64)
void k_nms(const float* __restrict__ sort_s, const float* __restrict__ sbox,
           const float* __restrict__ slbl, float* __restrict__ out) {
  int b = blockIdx.x;
  int lane = threadIdx.x;           // blockDim = 64 (one wave)
  __shared__ float4 kbox[NDET];     // kept boxes (class-offset space)
  __shared__ float  karea[NDET];
  __shared__ int    kidx[NDET];
  __shared__ float4 cbox[64];       // this group's candidates
  __shared__ float  carea[64];
  __shared__ u64    rows[64];       // intra-group suppression rows
  int n = 0;
  bool done = false;
  for (int base = 0; base < NCAND && !done; base += 64) {
    int ci = base + lane;
    float s = (ci < NCAND) ? sort_s[b * NCAND + ci] : -1.0f;
    bool valid = s > 0.0f;
    float4 q = make_float4(0.f, 0.f, 0.f, 0.f);
    float areaq = 0.f;
    if (valid) {
      q = ((const float4*)sbox)[b * NCAND + ci];
      float off = __fmul_rn(slbl[b * NCAND + ci], IMGSZ + 1.0f);
      q.x = __fadd_rn(q.x, off); q.y = __fadd_rn(q.y, off);
      q.z = __fadd_rn(q.z, off); q.w = __fadd_rn(q.w, off);
      areaq = __fmul_rn(__fsub_rn(q.z, q.x), __fsub_rn(q.w, q.y));
    }
    cbox[lane] = q; carea[lane] = areaq;   // stage for phase B
    __syncthreads();
    // phase A: test vs existing kept list, 8 independent LDS loads per window
    bool sup = false;
    int k = 0;
    for (; k + 8 <= n; k += 8) {
      float4 p0 = kbox[k+0], p1 = kbox[k+1], p2 = kbox[k+2], p3 = kbox[k+3];
      float4 p4 = kbox[k+4], p5 = kbox[k+5], p6 = kbox[k+6], p7 = kbox[k+7];
      float a0 = karea[k+0], a1 = karea[k+1], a2 = karea[k+2], a3 = karea[k+3];
      float a4 = karea[k+4], a5 = karea[k+5], a6 = karea[k+6], a7 = karea[k+7];
      sup = sup | iou_gt4(p0, a0, q, areaq) | iou_gt4(p1, a1, q, areaq)
                | iou_gt4(p2, a2, q, areaq) | iou_gt4(p3, a3, q, areaq)
                | iou_gt4(p4, a4, q, areaq) | iou_gt4(p5, a5, q, areaq)
                | iou_gt4(p6, a6, q, areaq) | iou_gt4(p7, a7, q, areaq);
    }
    for (; k < n; ++k) sup = sup | iou_gt4(kbox[k], karea[k], q, areaq);
    u64 pending = __ballot((int)(valid && !sup));
    // phase B: intra-group rows (lane suppresses j > lane), 4-wide batched LDS
    u64 row = 0;
    if ((pending >> lane) & 1ull) {
      for (int j0 = 0; j0 < 64; j0 += 4) {
        float4 q0 = cbox[j0+0], q1 = cbox[j0+1], q2 = cbox[j0+2], q3 = cbox[j0+3];
        float b0 = carea[j0+0], b1 = carea[j0+1], b2 = carea[j0+2], b3 = carea[j0+3];
        u64 bits = 0;
        if (j0+0 > lane && ((pending >> (j0+0)) & 1ull) && iou_gt4(q, areaq, q0, b0)) bits |= 1ull << (j0+0);
        if (j0+1 > lane && ((pending >> (j0+1)) & 1ull) && iou_gt4(q, areaq, q1, b1)) bits |= 1ull << (j0+1);
        if (j0+2 > lane && ((pending >> (j0+2)) & 1ull) && iou_gt4(q, areaq, q2, b2)) bits |= 1ull << (j0+2);
        if (j0+3 > lane && ((pending >> (j0+3)) & 1ull) && iou_gt4(q, areaq, q3, b3)) bits |= 1ull << (j0+3);
        row |= bits;
      }
    }
    rows[lane] = row;
    u64 nz = __ballot((int)(row != 0ull));   // lanes with any suppression bits
    __syncthreads();
    // phase C: wave-uniform greedy resolution; LDS row read only when needed
    u64 rem = pending;
    while (rem) {
      int r = __builtin_ctzll(rem);
      rem &= rem - 1;
      if (lane == r) {                       // owning lane writes; no broadcast needed
        kbox[n] = q; karea[n] = areaq; kidx[n] = base + r;
      }
      ++n;
      if (n == NDET) { done = true; break; }
      if ((nz >> r) & 1ull) rem &= ~rows[r]; // broadcast LDS read, rare
    }
    if (__any((int)(!valid))) done = true;   // sorted: rest of list invalid
    __syncthreads();                         // kbox writes visible for next group
  }
  // fused output: boxes [B,300,4] ++ scores [B,300] ++ labels [B,300]
  for (int k = lane; k < NDET; k += 64) {
    float bx0 = 0.f, bx1 = 0.f, bx2 = 0.f, bx3 = 0.f, sc = 0.f, lb = -1.0f;
    if (k < n) {
      int i = kidx[k];
      float4 v = ((const float4*)sbox)[b * NCAND + i];
      bx0 = v.x; bx1 = v.y; bx2 = v.z; bx3 = v.w;
      sc = sort_s[b * NCAND + i];
      lb = slbl[b * NCAND + i];
    }
    int idx = b * NDET + k;
    out[(size_t)idx * 4 + 0] = bx0;
    out[(size_t)idx * 4 + 1] = bx1;
    out[(size_t)idx * 4 + 2] = bx2;
    out[(size_t)idx * 4 + 3] = bx3;
    out[NB * NDET * 4 + idx] = sc;
    out[NB * NDET * 5 + idx] = lb;
  }
}

extern "C" void kernel_launch(void* const* d_in, const int* in_sizes, int n_in,
                              void* d_out, int out_size, void* d_ws, size_t ws_size,
                              hipStream_t stream) {
  const float* cls[NLEV]; const float* reg[NLEV]; const float* anc[NLEV];
  // dict order (cls,reg,anc per level) vs signature order (all cls, all reg, all anc)
  bool dict_order = (n_in >= 2) && (in_sizes[1] == 4 * NREGCH * 64 * 64);
  for (int l = 0; l < NLEV; ++l) {
    if (dict_order) {
      cls[l] = (const float*)d_in[3 * l + 0];
      reg[l] = (const float*)d_in[3 * l + 1];
      anc[l] = (const float*)d_in[3 * l + 2];
    } else {
      cls[l] = (const float*)d_in[l];
      reg[l] = (const float*)d_in[NLEV + l];
      anc[l] = (const float*)d_in[2 * NLEV + l];
    }
  }

  char* ws = (char*)d_ws;
  size_t off = 0;
  auto alloc = [&](size_t bytes) -> void* {
    void* p = ws + off;
    off = (off + bytes + 255) & ~(size_t)255;
    return p;
  };
  u32*   selcnt = (u32*)  alloc(20 * 4);
  u32*   hist   = (u32*)  alloc(20ULL * NBINS * 4);
  int*   cutbin = (int*)  alloc(20 * 4);
  u64*   sel    = (u64*)  alloc(20ULL * SELCAP * 8);
  float* cand_s = (float*)alloc((size_t)NB * NCAND * 4);
  u32*   cand_t = (u32*)  alloc((size_t)NB * NCAND * 4);
  float* sort_s = (float*)alloc((size_t)NB * NCAND * 4);
  u32*   sort_t = (u32*)  alloc((size_t)NB * NCAND * 4);
  float* sbox   = (float*)alloc((size_t)NB * NCAND * 16);
  float* slbl   = (float*)alloc((size_t)NB * NCAND * 4);
  (void)ws_size; (void)out_size;

  // zero selcnt + hist (contiguous from ws base through end of hist)
  size_t zero_bytes = (size_t)((char*)cutbin - (char*)selcnt);
  hipMemsetAsync(selcnt, 0, zero_bytes, stream);

  ClsPtrs cp;
  for (int l = 0; l < NLEV; ++l) cp.p[l] = cls[l];

  k_hist<<<NB * NCHUNK_IMG, 256, 0, stream>>>(cp, hist);
  k_cut<<<20, 256, 0, stream>>>(hist, cutbin);
  k_compact<<<NB * NCHUNK_IMG, 256, 0, stream>>>(cp, cutbin, selcnt, sel);
  k_seltop<<<20, 1024, 0, stream>>>(sel, selcnt, cand_s, cand_t);

  LevelPtrs lp;
  for (int l = 0; l < NLEV; ++l) { lp.reg[l] = reg[l]; lp.anc[l] = anc[l]; }
  k_merge<<<NB, 1024, 0, stream>>>(cand_s, cand_t, lp, sort_s, sort_t, sbox, slbl);
  k_nms<<<NB, 64, 0, stream>>>(sort_s, sbox, slbl, (float*)d_out);
}

// Round 7
// 257.774 us; speedup vs baseline: 5.1068x; 1.3560x over previous
//
#include <hip/hip_runtime.h>
#include <stdint.h>
#include <stddef.h>

typedef unsigned int u32;
typedef unsigned long long u64;

#define NB 4
#define NLEV 5
#define NCH 72      // A*C = 9*8
#define NREGCH 36   // A*4
#define TOPK 1000
#define NCAND 5000  // NLEV*TOPK
#define NDET 300
#define NBINS 16384       // sigmoid float bits >> 16 (max 0x3F80 = 16256)
#define SELCAP 4096
#define IMGSZ 512.0f
#define SCORE_TH 0.05f
#define NMS_TH 0.5f
#define BBOX_CLIP_F 4.135166556742356f

__constant__ int c_f[NLEV]    = {64, 32, 16, 8, 4};
__constant__ int c_Nloc[NLEV] = {4096, 1024, 256, 64, 16};
__constant__ int c_lg2[NLEV]  = {12, 10, 8, 6, 4};

// ---- XLA-CPU-style sigmoid: logistic(x) = 0.5 + 0.5*tanh(0.5*x), fast-tanh poly, no FMA ----
__device__ __forceinline__ float xla_tanh_f32(float x) {
  float ax = fabsf(x);
  float xc = fminf(fmaxf(x, -7.90531110763549805f), 7.90531110763549805f);
  float x2 = __fmul_rn(xc, xc);
  float p = -2.76076847742355e-16f;
  p = __fadd_rn(__fmul_rn(x2, p), 2.00018790482477e-13f);
  p = __fadd_rn(__fmul_rn(x2, p), -8.60467152213735e-11f);
  p = __fadd_rn(__fmul_rn(x2, p), 5.12229709037114e-08f);
  p = __fadd_rn(__fmul_rn(x2, p), 1.48572235717979e-05f);
  p = __fadd_rn(__fmul_rn(x2, p), 6.37261928875436e-04f);
  p = __fadd_rn(__fmul_rn(x2, p), 4.89352455891786e-03f);
  float num = __fmul_rn(xc, p);
  float q = 1.19825839466702e-06f;
  q = __fadd_rn(__fmul_rn(x2, q), 1.18534705686654e-04f);
  q = __fadd_rn(__fmul_rn(x2, q), 2.26843463243900e-03f);
  q = __fadd_rn(__fmul_rn(x2, q), 4.89352518554385e-03f);
  float r = __fdiv_rn(num, q);
  return (ax < 0.0004f) ? x : r;
}
__device__ __forceinline__ float sigmoid_ref(float x) {
  return __fadd_rn(0.5f, __fmul_rn(0.5f, xla_tanh_f32(__fmul_rn(0.5f, x))));
}

struct ClsPtrs { const float* p[NLEV]; };
struct LevelPtrs { const float* reg[NLEV]; const float* anc[NLEV]; };

// ---- K1: fused per-(b,level) selection: hist + cut + compact + exact rank top-1000 ----
__global__ __launch_bounds__(1024)
void k_select(ClsPtrs cp, float* __restrict__ cand_s, u32* __restrict__ cand_t) {
  int g = blockIdx.x;
  int b = g / NLEV, l = g % NLEV;
  int Nloc = c_Nloc[l], lg2 = c_lg2[l];
  int Nsc = Nloc * NCH;
  const float* cls = cp.p[l] + (size_t)b * Nsc;
  __shared__ union { u32 hist[NBINS]; u64 keys[SELCAP]; } sh;  // 64 KB
  __shared__ u32 part[1024];
  __shared__ u32 s_cnt;
  __shared__ int s_cut;
  int tid = threadIdx.x;
  int lane = tid & 63;
  u64 lowm = (1ull << lane) - 1ull;

  for (int i = tid; i < NBINS; i += 1024) sh.hist[i] = 0;
  __syncthreads();
  // pass 1: histogram of sigmoid bits >> 16
  for (int i = tid; i < Nsc; i += 1024) {
    float s = sigmoid_ref(cls[i]);
    atomicAdd(&sh.hist[__float_as_uint(s) >> 16], 1u);
  }
  __syncthreads();
  { u32 a = 0; for (int j = 0; j < 16; ++j) a += sh.hist[tid * 16 + j]; part[tid] = a; }
  __syncthreads();
  if (tid == 0) {
    u32 cum = 0; int cut = 0;
    for (int ch = 1023; ch >= 0; --ch) {        // cut is near the top; few iters
      if (cum + part[ch] >= TOPK) {
        u32 cc = cum;
        for (int bin = ch * 16 + 15;; --bin) { cc += sh.hist[bin]; if (cc >= TOPK) { cut = bin; break; } }
        break;
      }
      cum += part[ch];
    }
    s_cut = cut; s_cnt = 0;
  }
  __syncthreads();
  int cut = s_cut;
  // pass 2: compact bin>=cut elements into LDS keys (wave-aggregated append)
  for (int i = tid; i < Nsc; i += 1024) {
    float s = sigmoid_ref(cls[i]);
    u32 bits = __float_as_uint(s);
    bool sel = (int)(bits >> 16) >= cut;
    u64 mk = __ballot((int)sel);
    if (sel) {
      int ldr = __builtin_ctzll(mk);
      u32 base2 = 0;
      if (lane == ldr) base2 = atomicAdd(&s_cnt, (u32)__popcll(mk));
      base2 = (u32)__shfl((int)base2, ldr);
      u32 pos = base2 + (u32)__popcll(mk & lowm);
      if (pos < SELCAP) {
        int ch = i >> lg2;
        int loc = i & (Nloc - 1);
        u32 e = (u32)(loc * NCH + ch);   // flat score index ((y*f+x)*9+a)*8+c
        sh.keys[pos] = ((u64)bits << 32) | (u32)(~e);
      }
    }
  }
  __syncthreads();
  u32 m = s_cnt; if (m > SELCAP) m = SELCAP;
  int obase = b * NCAND + l * TOPK;
  // exact rank = count of strictly-greater keys (unique keys => stable permutation)
  for (u32 i = tid; i < m; i += 1024) {
    u64 k0 = sh.keys[i];
    u32 r = 0;
    for (u32 j = 0; j < m; ++j) r += (sh.keys[j] > k0) ? 1u : 0u;  // LDS broadcast scan
    if (r < TOPK) {
      cand_s[obase + r] = __uint_as_float((u32)(k0 >> 32));
      u32 e = ~((u32)k0);
      cand_t[obase + r] = ((u32)l << 19) | (e & 0x7FFFFu);
    }
  }
  for (u32 r = m + tid; r < TOPK; r += 1024) {   // safety fill (m>=TOPK in practice)
    cand_s[obase + r] = -1.0f;
    cand_t[obase + r] = ((u32)l << 19) | r;
  }
}

// IoU > thresh predicate — identical _rn sequence as reference; div only when inter>0
__device__ __forceinline__ bool iou_gt4(float4 p, float pa, float4 q, float qa) {
  float ltx = fmaxf(p.x, q.x), lty = fmaxf(p.y, q.y);
  float rx  = fminf(p.z, q.z), ry  = fminf(p.w, q.w);
  float ww = fmaxf(__fsub_rn(rx, ltx), 0.0f);
  float hh = fmaxf(__fsub_rn(ry, lty), 0.0f);
  float inter = __fmul_rn(ww, hh);
  bool res = false;
  if (inter > 0.0f) {
    float denom = fmaxf(__fsub_rn(__fadd_rn(pa, qa), inter), 1e-7f);
    res = __fdiv_rn(inter, denom) > NMS_TH;
  }
  return res;
}

// ---- K2: fused per-image merge+decode (all waves) then greedy NMS (wave 0) + output ----
__global__ __launch_bounds__(1024)
void k_detect(const float* __restrict__ cand_s, const u32* __restrict__ cand_t,
              LevelPtrs lp,
              float* __restrict__ sort_s, float* __restrict__ sbox, float* __restrict__ slbl,
              float* __restrict__ out) {
  __shared__ u64 keys[NCAND];       // 40 KB
  __shared__ float4 kbc[8][NDET];   // per-class kept boxes (offset space)  38.4 KB
  __shared__ float  karc[8][NDET];  // per-class kept areas                  9.6 KB
  __shared__ int    kidx[NDET];
  __shared__ float4 cbox[64];
  __shared__ float  carea[64];
  __shared__ u64    rowsh[64];
  __shared__ u32    kcnt[8];
  int b = blockIdx.x, tid = threadIdx.x;

  // ---- phase 1: 5-way merge by rank + fused decode (1024 threads) ----
  for (int i = tid; i < NCAND; i += 1024) {
    float s = cand_s[b * NCAND + i];
    u32 t = cand_t[b * NCAND + i];
    u32 hi = (s > SCORE_TH) ? __float_as_uint(s) : 0u;  // invalid -> sorts last
    keys[i] = ((u64)hi << 32) | (u32)(~t);
  }
  __syncthreads();
  for (int i = tid; i < NCAND; i += 1024) {
    u64 k0 = keys[i];
    int l = i / TOPK;
    int rank = i - l * TOPK;                 // own list: earlier entries are greater
    for (int L = 0; L < NLEV; ++L) {
      if (L == l) continue;
      const u64* A = keys + L * TOPK;        // desc-sorted (valid prefix), unique
      int lo = 0, hi2 = TOPK;                // count of A[j] > k0
      while (lo < hi2) { int mid = (lo + hi2) >> 1; if (A[mid] > k0) lo = mid + 1; else hi2 = mid; }
      rank += lo;
    }
    u32 t = ~((u32)k0);
    u32 hi = (u32)(k0 >> 32);
    float bx0 = 0.f, bx1 = 0.f, bx2 = 0.f, bx3 = 0.f, lbl = 0.f;
    if (hi) {
      sort_s[b * NCAND + rank] = __uint_as_float(hi);
      int lv = (int)(t >> 19);
      u32 e = t & 0x7FFFFu;
      int c = (int)(e & 7u);
      u32 anc = e >> 3;              // loc*9 + a
      int a = (int)(anc % 9u);
      int loc = (int)(anc / 9u);
      int f = c_f[lv];
      int Nloc = f * f;
      const float* rp = lp.reg[lv];
      const float* ap = lp.anc[lv] + (size_t)anc * 4;
      float r0 = rp[((size_t)b * NREGCH + (a * 4 + 0)) * Nloc + loc];
      float r1 = rp[((size_t)b * NREGCH + (a * 4 + 1)) * Nloc + loc];
      float r2 = rp[((size_t)b * NREGCH + (a * 4 + 2)) * Nloc + loc];
      float r3 = rp[((size_t)b * NREGCH + (a * 4 + 3)) * Nloc + loc];
      float a0 = ap[0], a1 = ap[1], a2 = ap[2], a3 = ap[3];
      float aw = __fsub_rn(a2, a0);
      float ah = __fsub_rn(a3, a1);
      float acx = __fadd_rn(a0, __fmul_rn(0.5f, aw));
      float acy = __fadd_rn(a1, __fmul_rn(0.5f, ah));
      float dw = fminf(r2, BBOX_CLIP_F);
      float dh = fminf(r3, BBOX_CLIP_F);
      float pcx = __fadd_rn(__fmul_rn(r0, aw), acx);
      float pcy = __fadd_rn(__fmul_rn(r1, ah), acy);
      float pw = __fmul_rn(expf(dw), aw);
      float ph = __fmul_rn(expf(dh), ah);
      float hx = __fmul_rn(0.5f, pw);
      float hy = __fmul_rn(0.5f, ph);
      bx0 = fminf(fmaxf(__fsub_rn(pcx, hx), 0.0f), IMGSZ);
      bx1 = fminf(fmaxf(__fsub_rn(pcy, hy), 0.0f), IMGSZ);
      bx2 = fminf(fmaxf(__fadd_rn(pcx, hx), 0.0f), IMGSZ);
      bx3 = fminf(fmaxf(__fadd_rn(pcy, hy), 0.0f), IMGSZ);
      lbl = (float)c;
    } else {
      sort_s[b * NCAND + rank] = -1.0f;
    }
    float4 v; v.x = bx0; v.y = bx1; v.z = bx2; v.w = bx3;
    ((float4*)sbox)[b * NCAND + rank] = v;
    slbl[b * NCAND + rank] = lbl;
  }
  __syncthreads();                  // phase-1 writes visible to wave 0
  if (tid >= 64) return;

  // ---- phase 2: greedy NMS, one wave, per-class kept lists ----
  int lane = tid;
  u64 lowm = (1ull << lane) - 1ull;
  if (lane < 8) kcnt[lane] = 0;
  int n = 0; bool done = false;
  // prefetch group 0
  float  s_nx = sort_s[b * NCAND + lane];
  float4 b_nx = ((const float4*)sbox)[b * NCAND + lane];
  float  l_nx = slbl[b * NCAND + lane];
  for (int base = 0; base < NCAND && !done; base += 64) {
    float s = s_nx; float4 v = b_nx; float lblf = l_nx;
    if (base + 64 < NCAND) {                 // prefetch next group
      int ci2 = base + 64 + lane;
      bool ok = ci2 < NCAND;
      s_nx = ok ? sort_s[b * NCAND + ci2] : -1.0f;
      b_nx = ok ? ((const float4*)sbox)[b * NCAND + ci2] : make_float4(0.f, 0.f, 0.f, 0.f);
      l_nx = ok ? slbl[b * NCAND + ci2] : 0.0f;
    }
    bool valid = s > 0.0f;
    int myc = (int)lblf;                     // 0 for invalid lanes (unused)
    float off = __fmul_rn(lblf, IMGSZ + 1.0f);
    float4 q;
    q.x = __fadd_rn(v.x, off); q.y = __fadd_rn(v.y, off);
    q.z = __fadd_rn(v.z, off); q.w = __fadd_rn(v.w, off);
    float areaq = __fmul_rn(__fsub_rn(q.z, q.x), __fsub_rn(q.w, q.y));
    cbox[lane] = q; carea[lane] = areaq;
    // same-class lane mask
    u64 cm_my = 0;
    for (int c = 0; c < 8; ++c) {
      u64 bc = __ballot((int)(valid && myc == c));
      if (myc == c) cm_my = bc;
    }
    // phase A: test vs kept list of MY class only (cross-class IoU provably 0)
    bool sup = false;
    if (valid) {
      int cnt = (int)kcnt[myc];
      const float4* kb = kbc[myc];
      const float*  ka = karc[myc];
      int k = 0;
      for (; k + 4 <= cnt; k += 4) {
        float4 p0 = kb[k], p1 = kb[k+1], p2 = kb[k+2], p3 = kb[k+3];
        float a0 = ka[k], a1 = ka[k+1], a2 = ka[k+2], a3 = ka[k+3];
        sup = sup | iou_gt4(p0, a0, q, areaq) | iou_gt4(p1, a1, q, areaq)
                  | iou_gt4(p2, a2, q, areaq) | iou_gt4(p3, a3, q, areaq);
      }
      for (; k < cnt; ++k) sup = sup | iou_gt4(kb[k], ka[k], q, areaq);
    }
    u64 pending = __ballot((int)(valid && !sup));
    // phase B: intra-group rows over same-class pending j > lane only
    u64 row = 0;
    if ((pending >> lane) & 1ull) {
      u64 mine = pending & cm_my & ~((2ull << lane) - 1ull);
      while (mine) {
        int j = __builtin_ctzll(mine); mine &= mine - 1ull;
        if (iou_gt4(q, areaq, cbox[j], carea[j])) row |= (1ull << j);
      }
    }
    rowsh[lane] = row;
    u64 nz = __ballot((int)(row != 0ull));
    // phase C
    if ((nz & pending) == 0ull) {            // no intra-group suppression: parallel append
      int avail = NDET - n;
      bool isp = ((pending >> lane) & 1ull) != 0;
      int grank = (int)__popcll(pending & lowm);
      u64 keptb = __ballot((int)(isp && grank < avail));
      if (isp && grank < avail) {
        kidx[n + grank] = base + lane;
        int crank = (int)__popcll(keptb & cm_my & lowm);
        int cb = (int)kcnt[myc];
        kbc[myc][cb + crank] = q; karc[myc][cb + crank] = areaq;
        if (crank == 0) kcnt[myc] = (u32)(cb + (int)__popcll(keptb & cm_my));
      }
      n += (int)__popcll(keptb);
      if (n >= NDET) done = true;
    } else {                                 // rare: serial greedy resolution
      u64 rem = pending;
      while (rem) {
        int r = __builtin_ctzll(rem); rem &= rem - 1ull;
        if (lane == r) {
          kidx[n] = base + r;
          int cb = (int)kcnt[myc];
          kbc[myc][cb] = q; karc[myc][cb] = areaq; kcnt[myc] = (u32)(cb + 1);
        }
        ++n;
        if (n == NDET) { done = true; break; }
        if ((nz >> r) & 1ull) rem &= ~rowsh[r];
      }
    }
    if (__any((int)(!valid))) done = true;   // sorted: rest of list invalid
  }
  // ---- output: boxes [B,300,4] ++ scores [B,300] ++ labels [B,300] ----
  for (int k = lane; k < NDET; k += 64) {
    float bx0 = 0.f, bx1 = 0.f, bx2 = 0.f, bx3 = 0.f, sc = 0.f, lb = -1.0f;
    if (k < n) {
      int i = kidx[k];
      float4 v = ((const float4*)sbox)[b * NCAND + i];
      bx0 = v.x; bx1 = v.y; bx2 = v.z; bx3 = v.w;
      sc = sort_s[b * NCAND + i];
      lb = slbl[b * NCAND + i];
    }
    int idx = b * NDET + k;
    out[(size_t)idx * 4 + 0] = bx0;
    out[(size_t)idx * 4 + 1] = bx1;
    out[(size_t)idx * 4 + 2] = bx2;
    out[(size_t)idx * 4 + 3] = bx3;
    out[NB * NDET * 4 + idx] = sc;
    out[NB * NDET * 5 + idx] = lb;
  }
}

extern "C" void kernel_launch(void* const* d_in, const int* in_sizes, int n_in,
                              void* d_out, int out_size, void* d_ws, size_t ws_size,
                              hipStream_t stream) {
  const float* cls[NLEV]; const float* reg[NLEV]; const float* anc[NLEV];
  bool dict_order = (n_in >= 2) && (in_sizes[1] == 4 * NREGCH * 64 * 64);
  for (int l = 0; l < NLEV; ++l) {
    if (dict_order) {
      cls[l] = (const float*)d_in[3 * l + 0];
      reg[l] = (const float*)d_in[3 * l + 1];
      anc[l] = (const float*)d_in[3 * l + 2];
    } else {
      cls[l] = (const float*)d_in[l];
      reg[l] = (const float*)d_in[NLEV + l];
      anc[l] = (const float*)d_in[2 * NLEV + l];
    }
  }

  char* ws = (char*)d_ws;
  size_t off = 0;
  auto alloc = [&](size_t bytes) -> void* {
    void* p = ws + off;
    off = (off + bytes + 255) & ~(size_t)255;
    return p;
  };
  float* cand_s = (float*)alloc((size_t)NB * NCAND * 4);
  u32*   cand_t = (u32*)  alloc((size_t)NB * NCAND * 4);
  float* sort_s = (float*)alloc((size_t)NB * NCAND * 4);
  float* sbox   = (float*)alloc((size_t)NB * NCAND * 16);
  float* slbl   = (float*)alloc((size_t)NB * NCAND * 4);
  (void)ws_size; (void)out_size;

  ClsPtrs cp;
  for (int l = 0; l < NLEV; ++l) cp.p[l] = cls[l];
  LevelPtrs lp;
  for (int l = 0; l < NLEV; ++l) { lp.reg[l] = reg[l]; lp.anc[l] = anc[l]; }

  k_select<<<NB * NLEV, 1024, 0, stream>>>(cp, cand_s, cand_t);
  k_detect<<<NB, 1024, 0, stream>>>(cand_s, cand_t, lp, sort_s, sbox, slbl, (float*)d_out);
}